// Round 1
// baseline (403.868 us; speedup 1.0000x reference)
//
#include <hip/hip_runtime.h>
#include <cstdint>

typedef __attribute__((ext_vector_type(8))) short short8;
typedef __attribute__((ext_vector_type(8))) __bf16 bf16x8;
typedef __attribute__((ext_vector_type(4))) float f32x4;

__device__ __forceinline__ short f2bf(float f) {
  union { float f; uint32_t u; } v; v.f = f;
  uint32_t u = v.u + 0x7FFFu + ((v.u >> 16) & 1u);  // RNE
  return (short)(u >> 16);
}

__device__ __forceinline__ void gload_lds16(const void* g, void* l) {
  __builtin_amdgcn_global_load_lds(
      (const __attribute__((address_space(1))) void*)(uintptr_t)g,
      (__attribute__((address_space(3))) void*)(uint32_t)(uintptr_t)l,
      16, 0, 0);
}

// ---------------- conversion kernels ----------------

__global__ __launch_bounds__(256) void cvt_f32_bf16(const float* __restrict__ s,
                                                    short* __restrict__ d, long n) {
  long i = ((long)blockIdx.x * 256 + threadIdx.x) * 8;
  if (i + 8 > n) return;
  const float4 a = *(const float4*)(s + i);
  const float4 b = *(const float4*)(s + i + 4);
  short8 o;
  o[0] = f2bf(a.x); o[1] = f2bf(a.y); o[2] = f2bf(a.z); o[3] = f2bf(a.w);
  o[4] = f2bf(b.x); o[5] = f2bf(b.y); o[6] = f2bf(b.z); o[7] = f2bf(b.w);
  *(short8*)(d + i) = o;
}

// Mt[b][e][d] = bf16(M[b][d][e])
__global__ __launch_bounds__(256) void cvtT_M(const float* __restrict__ Msrc,
                                              short* __restrict__ Mt) {
  __shared__ short t[64][65];
  const int tid = threadIdx.x;
  const long bofs = (long)blockIdx.z * 1024 * 1024;
  const int d0 = blockIdx.x * 64, e0 = blockIdx.y * 64;
#pragma unroll
  for (int k = 0; k < 16; ++k) {
    int idx = k * 256 + tid; int r = idx >> 6, c = idx & 63;
    t[r][c] = f2bf(Msrc[bofs + (long)(d0 + r) * 1024 + e0 + c]);
  }
  __syncthreads();
#pragma unroll
  for (int k = 0; k < 16; ++k) {
    int idx = k * 256 + tid; int r = idx >> 6, c = idx & 63;
    Mt[bofs + (long)(e0 + r) * 1024 + d0 + c] = t[c][r];
  }
}

// Vt[b][h][dh][s] = V[b][s][h*64+dh]
__global__ __launch_bounds__(256) void transposeV(const short* __restrict__ V,
                                                  short* __restrict__ Vt) {
  __shared__ short t[64][65];
  const int tid = threadIdx.x;
  const int s0 = blockIdx.x * 64, h = blockIdx.y;
  const long b = blockIdx.z;
  const short* src = V + (b * 2048) * 1024 + h * 64;
  short* dst = Vt + ((b * 16 + h) * 64) * 2048;
#pragma unroll
  for (int k = 0; k < 16; ++k) {
    int idx = k * 256 + tid; int r = idx >> 6, c = idx & 63;  // r = s row, c = dh
    t[r][c] = src[(long)(s0 + r) * 1024 + c];
  }
  __syncthreads();
#pragma unroll
  for (int k = 0; k < 16; ++k) {
    int idx = k * 256 + tid; int r = idx >> 6, c = idx & 63;  // r = dh, c = s
    dst[(long)r * 2048 + s0 + c] = t[c][r];
  }
}

// ---------------- GEMM: C[M][N] = A[M][K] * B[N][K]^T (bf16 in, f32 acc) ----------------

template <typename CT>
__global__ __launch_bounds__(256) void gemm_bt(
    const short* __restrict__ A, const short* __restrict__ B, CT* __restrict__ C,
    int M, int N, int K, long sA, long sB, long sC) {
  __shared__ __align__(16) short As[128 * 32];
  __shared__ __align__(16) short Bs[128 * 32];
  const int tid = threadIdx.x;
  const int w = tid >> 6, lane = tid & 63;
  const int wr = w >> 1, wc = w & 1;
  const short* Ab = A + (long)blockIdx.z * sA + (long)blockIdx.x * 128 * K;
  const short* Bb = B + (long)blockIdx.z * sB + (long)blockIdx.y * 128 * K;

  f32x4 acc[4][4];
#pragma unroll
  for (int i = 0; i < 4; ++i)
#pragma unroll
    for (int j = 0; j < 4; ++j) acc[i][j] = {0.f, 0.f, 0.f, 0.f};

  const int srow = lane >> 2;                      // row within 16-row chunk
  const int scol = ((lane & 3) ^ (srow & 3)) * 8;  // pre-swizzled source col (shorts)

  for (int k0 = 0; k0 < K; k0 += 32) {
    __syncthreads();
#pragma unroll
    for (int c = 0; c < 2; ++c) {
      const int chunk = w * 2 + c;
      const long gr = (long)(chunk * 16 + srow);
      gload_lds16(Ab + gr * K + k0 + scol, &As[chunk * 512]);
      gload_lds16(Bb + gr * K + k0 + scol, &Bs[chunk * 512]);
    }
    __syncthreads();
    bf16x8 af[4], bfr[4];
#pragma unroll
    for (int mf = 0; mf < 4; ++mf) {
      const int r = wr * 64 + mf * 16 + (lane & 15);
      const int cb = (lane >> 4) ^ (r & 3);
      af[mf] = *(const bf16x8*)&As[r * 32 + cb * 8];
    }
#pragma unroll
    for (int nf = 0; nf < 4; ++nf) {
      const int r = wc * 64 + nf * 16 + (lane & 15);
      const int cb = (lane >> 4) ^ (r & 3);
      bfr[nf] = *(const bf16x8*)&Bs[r * 32 + cb * 8];
    }
#pragma unroll
    for (int mf = 0; mf < 4; ++mf)
#pragma unroll
      for (int nf = 0; nf < 4; ++nf)
        acc[mf][nf] =
            __builtin_amdgcn_mfma_f32_16x16x32_bf16(af[mf], bfr[nf], acc[mf][nf], 0, 0, 0);
  }

  CT* Cb = C + (long)blockIdx.z * sC;
  const int r0 = (lane >> 4) * 4, cc = lane & 15;
#pragma unroll
  for (int mf = 0; mf < 4; ++mf)
#pragma unroll
    for (int i = 0; i < 4; ++i) {
      const long row = (long)blockIdx.x * 128 + wr * 64 + mf * 16 + r0 + i;
#pragma unroll
      for (int nf = 0; nf < 4; ++nf) {
        const long col = (long)blockIdx.y * 128 + wc * 64 + nf * 16 + cc;
        float v = acc[mf][nf][i];
        if constexpr (__is_same(CT, short))
          Cb[row * (long)N + col] = f2bf(v);
        else
          Cb[row * (long)N + col] = v;
      }
    }
}

// ---------------- flash attention ----------------
// grid: (S/64, H, B); 256 threads = 4 waves, each wave owns 16 q-rows.

__global__ __launch_bounds__(256) void flash_attn(
    const short* __restrict__ QM, const short* __restrict__ Kb,
    const short* __restrict__ Vt, const float* __restrict__ mask,
    short* __restrict__ AO) {
  constexpr int S = 2048, D = 1024, DH = 64;
  __shared__ __align__(16) short Ks[64 * 64];
  __shared__ __align__(16) short Vs[64 * 64];
  __shared__ __align__(16) short Ps[4][16 * 64];
  const int tid = threadIdx.x;
  const int w = tid >> 6, lane = tid & 63;
  const int q0 = blockIdx.x * 64;
  const int h = blockIdx.y;
  const long b = blockIdx.z;

  const short* QMb = QM + (b * S) * D + h * DH;
  const short* Kbp = Kb + (b * S) * D + h * DH;
  const short* Vtp = Vt + ((b * 16 + h) * DH) * S;

  // Q fragments (A-operand): rows q0 + w*16 .. +16, held in registers for all KV tiles
  bf16x8 qf[2];
#pragma unroll
  for (int ks = 0; ks < 2; ++ks)
    qf[ks] = *(const bf16x8*)(QMb + (long)(q0 + w * 16 + (lane & 15)) * D + ks * 32 +
                              (lane >> 4) * 8);

  f32x4 acc_o[4];
#pragma unroll
  for (int f = 0; f < 4; ++f) acc_o[f] = {0.f, 0.f, 0.f, 0.f};
  float m_run[4], l_run[4];
#pragma unroll
  for (int i = 0; i < 4; ++i) { m_run[i] = -1e30f; l_run[i] = 0.f; }

  const int srow8 = lane >> 3;                       // row within 8-row chunk
  const int scol8 = ((lane & 7) ^ (srow8 & 7)) * 8;  // pre-swizzled source col (shorts)
  const int r0 = (lane >> 4) * 4, cc = lane & 15;
  short* myP = &Ps[w][0];

  for (int t0 = 0; t0 < S; t0 += 64) {
    __syncthreads();
#pragma unroll
    for (int c = 0; c < 2; ++c) {
      const int chunk = w * 2 + c;
      const int row = chunk * 8 + srow8;
      gload_lds16(Kbp + (long)(t0 + row) * D + scol8, &Ks[chunk * 512]);
      gload_lds16(Vtp + (long)row * S + t0 + scol8, &Vs[chunk * 512]);
    }
    __syncthreads();

    // S-tile = Q K^T  (16 q-rows x 64 t-cols per wave)
    f32x4 sacc[4];
#pragma unroll
    for (int nf = 0; nf < 4; ++nf) sacc[nf] = {0.f, 0.f, 0.f, 0.f};
#pragma unroll
    for (int ks = 0; ks < 2; ++ks) {
#pragma unroll
      for (int nf = 0; nf < 4; ++nf) {
        const int r = nf * 16 + (lane & 15);
        const int blk = (ks * 4 + (lane >> 4)) ^ (r & 7);
        bf16x8 kf = *(const bf16x8*)&Ks[r * 64 + blk * 8];
        sacc[nf] = __builtin_amdgcn_mfma_f32_16x16x32_bf16(qf[ks], kf, sacc[nf], 0, 0, 0);
      }
    }

    // scale + clip + mask; rowmax (row i lives in the 16 lanes sharing lane>>4)
    float sv[4][4];
    float pmax[4];
#pragma unroll
    for (int i = 0; i < 4; ++i) pmax[i] = -1e30f;
    const long mrow0 = (long)(q0 + w * 16 + r0) * S + t0 + cc;
#pragma unroll
    for (int nf = 0; nf < 4; ++nf)
#pragma unroll
      for (int i = 0; i < 4; ++i) {
        float s = sacc[nf][i] * 0.125f;
        s = fminf(fmaxf(s, -50.f), 50.f);
        s += mask[mrow0 + (long)i * S + nf * 16];
        sv[nf][i] = s;
        pmax[i] = fmaxf(pmax[i], s);
      }
#pragma unroll
    for (int i = 0; i < 4; ++i) {
      float mx = pmax[i];
#pragma unroll
      for (int off = 1; off < 16; off <<= 1) mx = fmaxf(mx, __shfl_xor(mx, off));
      pmax[i] = mx;
    }

    float alpha[4];
#pragma unroll
    for (int i = 0; i < 4; ++i) {
      float mnew = fmaxf(m_run[i], pmax[i]);
      alpha[i] = __expf(m_run[i] - mnew);
      m_run[i] = mnew;
    }

    float psum[4] = {0.f, 0.f, 0.f, 0.f};
#pragma unroll
    for (int nf = 0; nf < 4; ++nf)
#pragma unroll
      for (int i = 0; i < 4; ++i) {
        float pv = __expf(sv[nf][i] - m_run[i]);
        psum[i] += pv;
        const int prow = r0 + i;
        const int col = nf * 16 + cc;
        const int blk = (col >> 3) ^ (prow & 7);
        myP[prow * 64 + blk * 8 + (col & 7)] = f2bf(pv);  // swizzled wave-private P
      }
#pragma unroll
    for (int i = 0; i < 4; ++i) {
      float s = psum[i];
#pragma unroll
      for (int off = 1; off < 16; off <<= 1) s += __shfl_xor(s, off);
      l_run[i] = l_run[i] * alpha[i] + s;
    }
#pragma unroll
    for (int f = 0; f < 4; ++f)
#pragma unroll
      for (int i = 0; i < 4; ++i) acc_o[f][i] *= alpha[i];

    // PV: O += P[16 x 64] * V[64 x 64]
#pragma unroll
    for (int ts = 0; ts < 2; ++ts) {
      const int prow = lane & 15;
      const int pblk = (ts * 4 + (lane >> 4)) ^ (prow & 7);
      bf16x8 pf = *(const bf16x8*)&myP[prow * 64 + pblk * 8];
#pragma unroll
      for (int f = 0; f < 4; ++f) {
        const int vr = f * 16 + (lane & 15);
        const int vblk = (ts * 4 + (lane >> 4)) ^ (vr & 7);
        bf16x8 vf = *(const bf16x8*)&Vs[vr * 64 + vblk * 8];
        acc_o[f] = __builtin_amdgcn_mfma_f32_16x16x32_bf16(pf, vf, acc_o[f], 0, 0, 0);
      }
    }
  }

  // epilogue: normalize and store bf16
  short* AOp = AO + (b * S) * D + h * DH;
#pragma unroll
  for (int f = 0; f < 4; ++f)
#pragma unroll
    for (int i = 0; i < 4; ++i) {
      const float o = acc_o[f][i] / l_run[i];
      AOp[(long)(q0 + w * 16 + r0 + i) * D + f * 16 + cc] = f2bf(o);
    }
}

// ---------------- launch ----------------

extern "C" void kernel_launch(void* const* d_in, const int* in_sizes, int n_in,
                              void* d_out, int out_size, void* d_ws, size_t ws_size,
                              hipStream_t stream) {
  const float* x = (const float*)d_in[0];
  const float* M = (const float*)d_in[1];
  const float* mask = (const float*)d_in[2];
  const float* Wq = (const float*)d_in[3];
  const float* Wk = (const float*)d_in[4];
  const float* Wv = (const float*)d_in[5];
  const float* Wo = (const float*)d_in[6];
  float* out = (float*)d_out;

  constexpr long S = 2048, D = 1024;
  constexpr long NX = 4 * S * D;  // 8388608
  constexpr long NW = D * D;      // 1048576

  short* p = (short*)d_ws;
  short* xb = p;  p += NX;
  short* wqb = p; p += NW;
  short* wkb = p; p += NW;
  short* wvb = p; p += NW;
  short* wob = p; p += NW;
  short* Mtb = p; p += 4 * NW;
  short* Qb = p;  p += NX;
  short* Kb = p;  p += NX;
  short* Vb = p;  p += NX;
  short* QMb = p; p += NX;
  short* Vtb = p; p += NX;
  short* AOb = Qb;  // Q dead after QM -> reuse for attention output

  cvt_f32_bf16<<<NX / 2048, 256, 0, stream>>>(x, xb, NX);
  cvt_f32_bf16<<<NW / 2048, 256, 0, stream>>>(Wq, wqb, NW);
  cvt_f32_bf16<<<NW / 2048, 256, 0, stream>>>(Wk, wkb, NW);
  cvt_f32_bf16<<<NW / 2048, 256, 0, stream>>>(Wv, wvb, NW);
  cvt_f32_bf16<<<NW / 2048, 256, 0, stream>>>(Wo, wob, NW);
  cvtT_M<<<dim3(16, 16, 4), 256, 0, stream>>>(M, Mtb);

  // Q = x Wq^T ; K = x Wk^T ; V = x Wv^T   (M=8192, N=1024, K=1024)
  gemm_bt<short><<<dim3(64, 8, 1), 256, 0, stream>>>(xb, wqb, Qb, 8192, 1024, 1024, 0, 0, 0);
  gemm_bt<short><<<dim3(64, 8, 1), 256, 0, stream>>>(xb, wkb, Kb, 8192, 1024, 1024, 0, 0, 0);
  gemm_bt<short><<<dim3(64, 8, 1), 256, 0, stream>>>(xb, wvb, Vb, 8192, 1024, 1024, 0, 0, 0);
  // QM = Q @ M per batch (Mt is [e][d])
  gemm_bt<short><<<dim3(16, 8, 4), 256, 0, stream>>>(Qb, Mtb, QMb, 2048, 1024, 1024,
                                                     S * D, D * D, S * D);
  transposeV<<<dim3(32, 16, 4), 256, 0, stream>>>(Vb, Vtb);
  flash_attn<<<dim3(32, 16, 4), 256, 0, stream>>>(QMb, Kb, Vtb, mask, AOb);
  // out = AO @ Wo^T (f32 store)
  gemm_bt<float><<<dim3(64, 8, 1), 256, 0, stream>>>(AOb, wob, out, 8192, 1024, 1024, 0, 0, 0);
}

// Round 3
// 311.957 us; speedup vs baseline: 1.2946x; 1.2946x over previous
//
#include <hip/hip_runtime.h>
#include <cstdint>

typedef __attribute__((ext_vector_type(8))) short short8;
typedef __attribute__((ext_vector_type(8))) __bf16 bf16x8;
typedef __attribute__((ext_vector_type(4))) float f32x4;

__device__ __forceinline__ short f2bf(float f) {
  union { float f; uint32_t u; } v; v.f = f;
  uint32_t u = v.u + 0x7FFFu + ((v.u >> 16) & 1u);  // RNE
  return (short)(u >> 16);
}

__device__ __forceinline__ float exp2_fast(float x) {
  return __builtin_amdgcn_exp2f(x);  // v_exp_f32 (native 2^x)
}

__device__ __forceinline__ uint32_t cvt_pk_bf16(float lo, float hi) {
  uint32_t r;
  asm("v_cvt_pk_bf16_f32 %0, %1, %2" : "=v"(r) : "v"(lo), "v"(hi));
  return r;
}

__device__ __forceinline__ void gload_lds16(const void* g, void* l) {
  __builtin_amdgcn_global_load_lds(
      (const __attribute__((address_space(1))) void*)(uintptr_t)g,
      (__attribute__((address_space(3))) void*)(uint32_t)(uintptr_t)l,
      16, 0, 0);
}

// ---------------- conversion kernels ----------------

__global__ __launch_bounds__(256) void cvt_f32_bf16(const float* __restrict__ s,
                                                    short* __restrict__ d, long n) {
  long i = ((long)blockIdx.x * 256 + threadIdx.x) * 8;
  if (i + 8 > n) return;
  const float4 a = *(const float4*)(s + i);
  const float4 b = *(const float4*)(s + i + 4);
  short8 o;
  o[0] = f2bf(a.x); o[1] = f2bf(a.y); o[2] = f2bf(a.z); o[3] = f2bf(a.w);
  o[4] = f2bf(b.x); o[5] = f2bf(b.y); o[6] = f2bf(b.z); o[7] = f2bf(b.w);
  *(short8*)(d + i) = o;
}

// Mt[b][e][d] = bf16(M[b][d][e])
__global__ __launch_bounds__(256) void cvtT_M(const float* __restrict__ Msrc,
                                              short* __restrict__ Mt) {
  __shared__ short t[64][65];
  const int tid = threadIdx.x;
  const long bofs = (long)blockIdx.z * 1024 * 1024;
  const int d0 = blockIdx.x * 64, e0 = blockIdx.y * 64;
#pragma unroll
  for (int k = 0; k < 16; ++k) {
    int idx = k * 256 + tid; int r = idx >> 6, c = idx & 63;
    t[r][c] = f2bf(Msrc[bofs + (long)(d0 + r) * 1024 + e0 + c]);
  }
  __syncthreads();
#pragma unroll
  for (int k = 0; k < 16; ++k) {
    int idx = k * 256 + tid; int r = idx >> 6, c = idx & 63;
    Mt[bofs + (long)(e0 + r) * 1024 + d0 + c] = t[c][r];
  }
}

// Vt[b][h][dh][s] = V[b][s][h*64+dh]
__global__ __launch_bounds__(256) void transposeV(const short* __restrict__ V,
                                                  short* __restrict__ Vt) {
  __shared__ short t[64][65];
  const int tid = threadIdx.x;
  const int s0 = blockIdx.x * 64, h = blockIdx.y;
  const long b = blockIdx.z;
  const short* src = V + (b * 2048) * 1024 + h * 64;
  short* dst = Vt + ((b * 16 + h) * 64) * 2048;
#pragma unroll
  for (int k = 0; k < 16; ++k) {
    int idx = k * 256 + tid; int r = idx >> 6, c = idx & 63;  // r = s row, c = dh
    t[r][c] = src[(long)(s0 + r) * 1024 + c];
  }
  __syncthreads();
#pragma unroll
  for (int k = 0; k < 16; ++k) {
    int idx = k * 256 + tid; int r = idx >> 6, c = idx & 63;  // r = dh, c = s
    dst[(long)r * 2048 + s0 + c] = t[c][r];
  }
}

// mask tile flags: flags[qt*32+tt] = any nonzero in 64x64 tile
__global__ __launch_bounds__(256) void mask_flags(const float* __restrict__ mask,
                                                  int* __restrict__ flags) {
  __shared__ int f;
  const int tid = threadIdx.x;
  if (tid == 0) f = 0;
  __syncthreads();
  const int qt = blockIdx.x, tt = blockIdx.y;
  const float* base = mask + (long)qt * 64 * 2048 + tt * 64;
  const int r = tid >> 2, c = (tid & 3) * 16;
  bool nz = false;
#pragma unroll
  for (int k = 0; k < 4; ++k) {
    float4 v = *(const float4*)(base + (long)r * 2048 + c + k * 4);
    nz = nz | (v.x != 0.f) | (v.y != 0.f) | (v.z != 0.f) | (v.w != 0.f);
  }
  if (nz) f = 1;
  __syncthreads();
  if (tid == 0) flags[qt * 32 + tt] = f;
}

// ---------------- GEMM: C[M][N] = A[M][K] * B[N][K]^T (bf16 in, f32 acc) ----------------

template <typename CT>
__global__ __launch_bounds__(256) void gemm_bt(
    const short* __restrict__ A, const short* __restrict__ B, CT* __restrict__ C,
    int M, int N, int K, long sA, long sB, long sC) {
  __shared__ __align__(16) short As[128 * 32];
  __shared__ __align__(16) short Bs[128 * 32];
  const int tid = threadIdx.x;
  const int w = tid >> 6, lane = tid & 63;
  const int wr = w >> 1, wc = w & 1;
  const short* Ab = A + (long)blockIdx.z * sA + (long)blockIdx.x * 128 * K;
  const short* Bb = B + (long)blockIdx.z * sB + (long)blockIdx.y * 128 * K;

  f32x4 acc[4][4];
#pragma unroll
  for (int i = 0; i < 4; ++i)
#pragma unroll
    for (int j = 0; j < 4; ++j) acc[i][j] = {0.f, 0.f, 0.f, 0.f};

  const int srow = lane >> 2;                      // row within 16-row chunk
  const int scol = ((lane & 3) ^ (srow & 3)) * 8;  // pre-swizzled source col (shorts)

  for (int k0 = 0; k0 < K; k0 += 32) {
    __syncthreads();
#pragma unroll
    for (int c = 0; c < 2; ++c) {
      const int chunk = w * 2 + c;
      const long gr = (long)(chunk * 16 + srow);
      gload_lds16(Ab + gr * K + k0 + scol, &As[chunk * 512]);
      gload_lds16(Bb + gr * K + k0 + scol, &Bs[chunk * 512]);
    }
    __syncthreads();
    bf16x8 af[4], bfr[4];
#pragma unroll
    for (int mf = 0; mf < 4; ++mf) {
      const int r = wr * 64 + mf * 16 + (lane & 15);
      const int cb = (lane >> 4) ^ (r & 3);
      af[mf] = *(const bf16x8*)&As[r * 32 + cb * 8];
    }
#pragma unroll
    for (int nf = 0; nf < 4; ++nf) {
      const int r = wc * 64 + nf * 16 + (lane & 15);
      const int cb = (lane >> 4) ^ (r & 3);
      bfr[nf] = *(const bf16x8*)&Bs[r * 32 + cb * 8];
    }
#pragma unroll
    for (int mf = 0; mf < 4; ++mf)
#pragma unroll
      for (int nf = 0; nf < 4; ++nf)
        acc[mf][nf] =
            __builtin_amdgcn_mfma_f32_16x16x32_bf16(af[mf], bfr[nf], acc[mf][nf], 0, 0, 0);
  }

  CT* Cb = C + (long)blockIdx.z * sC;
  const int r0 = (lane >> 4) * 4, cc = lane & 15;
#pragma unroll
  for (int mf = 0; mf < 4; ++mf)
#pragma unroll
    for (int i = 0; i < 4; ++i) {
      const long row = (long)blockIdx.x * 128 + wr * 64 + mf * 16 + r0 + i;
#pragma unroll
      for (int nf = 0; nf < 4; ++nf) {
        const long col = (long)blockIdx.y * 128 + wc * 64 + nf * 16 + cc;
        float v = acc[mf][nf][i];
        if constexpr (__is_same(CT, short))
          Cb[row * (long)N + col] = f2bf(v);
        else
          Cb[row * (long)N + col] = v;
      }
    }
}

// ---------------- flash attention (swapped QK^T, O^T accumulator) ----------------
// grid: (S/64, H, B); 256 threads = 4 waves, each wave owns 16 q-rows.
// S-tile computed transposed: sacc[nf] = mfma(K, Q) -> S^T[t][q], q = lane&15.
// Softmax in-register per q (15 fmax + 2 shfl); alpha/l are lane-scalars.
// P packed via v_cvt_pk_bf16_f32 into swizzled wave-private LDS [q][t].
// PV: O^T = mfma(Vt, P). Epilogue transposes O^T->O via LDS, coalesced stores.

__global__ __launch_bounds__(256) void flash_attn(
    const short* __restrict__ QM, const short* __restrict__ Kb,
    const short* __restrict__ Vt, const float* __restrict__ mask,
    const int* __restrict__ mflags, short* __restrict__ AO) {
  constexpr int S = 2048, D = 1024;
  constexpr float LOG2E = 1.44269504088896f;
  constexpr float C1 = 0.125f * LOG2E;   // 1/sqrt(64) * log2(e)
  constexpr float CLIP = 50.0f * LOG2E;
  __shared__ __align__(16) short Ks[64 * 64];
  __shared__ __align__(16) short Vs[64 * 64];
  __shared__ __align__(16) short Ps[4][16 * 64];
  const int tid = threadIdx.x;
  const int w = tid >> 6, lane = tid & 63;
  const int q = lane & 15, g = lane >> 4;
  const int q0 = blockIdx.x * 64;
  const int h = blockIdx.y;
  const long b = blockIdx.z;

  const short* QMb = QM + (b * S) * D + h * 64;
  const short* Kbp = Kb + (b * S) * D + h * 64;
  const short* Vtp = Vt + ((b * 16 + h) * 64) * S;
  const int* flagrow = mflags + (q0 >> 6) * 32;

  // Q fragments (B-operand): B[j=q][k], j = lane&15, k = (lane>>4)*8+reg
  bf16x8 qf[2];
#pragma unroll
  for (int ks = 0; ks < 2; ++ks)
    qf[ks] = *(const bf16x8*)(QMb + (long)(q0 + w * 16 + q) * D + ks * 32 + g * 8);

  f32x4 acc[4];  // O^T: rows d = f*16 + 4g + i, col q
#pragma unroll
  for (int f = 0; f < 4; ++f) acc[f] = {0.f, 0.f, 0.f, 0.f};
  float m_run = -1e30f, l_run = 0.f;  // per-lane, for this lane's q (log2 domain)

  const int srow8 = lane >> 3;                       // staging row within 8-row chunk
  const int scol8 = ((lane & 7) ^ (srow8 & 7)) * 8;  // pre-swizzled source col
  short* Pw = &Ps[w][0];
  const int psw = (q & 7) << 3;  // P chunk swizzle (shorts)

  for (int t0 = 0; t0 < S; t0 += 64) {
    __syncthreads();
#pragma unroll
    for (int c = 0; c < 2; ++c) {
      const int chunk = w * 2 + c;
      const int row = chunk * 8 + srow8;
      gload_lds16(Kbp + (long)(t0 + row) * D + scol8, &Ks[chunk * 512]);
      gload_lds16(Vtp + (long)row * S + t0 + scol8, &Vs[chunk * 512]);
    }
    __syncthreads();

    // S^T tile: sacc[nf] = K Q^T, rows t = nf*16 + 4g + i, col q
    f32x4 sacc[4];
#pragma unroll
    for (int nf = 0; nf < 4; ++nf) sacc[nf] = {0.f, 0.f, 0.f, 0.f};
#pragma unroll
    for (int ks = 0; ks < 2; ++ks) {
#pragma unroll
      for (int nf = 0; nf < 4; ++nf) {
        const int r = nf * 16 + q;
        const int blk = (ks * 4 + g) ^ (r & 7);
        bf16x8 kf = *(const bf16x8*)&Ks[r * 64 + blk * 8];
        sacc[nf] = __builtin_amdgcn_mfma_f32_16x16x32_bf16(kf, qf[ks], sacc[nf], 0, 0, 0);
      }
    }

    // scale + clip (+ mask) in log2 domain; in-register row max
    float sv[4][4];
    float pmax = -1e30f;
    if (__builtin_expect(flagrow[t0 >> 6], 0)) {
      const float* mrow = mask + (long)(q0 + w * 16 + q) * S + t0;
#pragma unroll
      for (int nf = 0; nf < 4; ++nf) {
        float4 mv = *(const float4*)(mrow + nf * 16 + 4 * g);
        const float* mp = &mv.x;
#pragma unroll
        for (int i = 0; i < 4; ++i) {
          float s = fminf(fmaxf(sacc[nf][i] * C1, -CLIP), CLIP) + LOG2E * mp[i];
          sv[nf][i] = s;
          pmax = fmaxf(pmax, s);
        }
      }
    } else {
#pragma unroll
      for (int nf = 0; nf < 4; ++nf)
#pragma unroll
        for (int i = 0; i < 4; ++i) {
          float s = fminf(fmaxf(sacc[nf][i] * C1, -CLIP), CLIP);
          sv[nf][i] = s;
          pmax = fmaxf(pmax, s);
        }
    }
    pmax = fmaxf(pmax, __shfl_xor(pmax, 16));
    pmax = fmaxf(pmax, __shfl_xor(pmax, 32));

    const float m_new = fmaxf(m_run, pmax);
    const float alpha = exp2_fast(m_run - m_new);
    m_run = m_new;

    float psum = 0.f;
#pragma unroll
    for (int nf = 0; nf < 4; ++nf)
#pragma unroll
      for (int i = 0; i < 4; ++i) {
        float p = exp2_fast(sv[nf][i] - m_run);
        psum += p;
        sv[nf][i] = p;
      }
#pragma unroll
    for (int nf = 0; nf < 4; ++nf) {
      uint2 u;
      u.x = cvt_pk_bf16(sv[nf][0], sv[nf][1]);
      u.y = cvt_pk_bf16(sv[nf][2], sv[nf][3]);
      *(uint2*)&Pw[q * 64 + ((nf * 16 + 4 * g) ^ psw)] = u;
    }
    psum += __shfl_xor(psum, 16);
    psum += __shfl_xor(psum, 32);
    l_run = l_run * alpha + psum;
#pragma unroll
    for (int f = 0; f < 4; ++f)
#pragma unroll
      for (int i = 0; i < 4; ++i) acc[f][i] *= alpha;

    // O^T += V^T P : A = Vt frag (rows d), B = P frag (j=q, k=t)
#pragma unroll
    for (int ts = 0; ts < 2; ++ts) {
      bf16x8 pfr = *(const bf16x8*)&Pw[q * 64 + ((ts * 32 + 8 * g) ^ psw)];
#pragma unroll
      for (int f = 0; f < 4; ++f) {
        const int vr = f * 16 + q;
        const int vblk = (ts * 4 + g) ^ (vr & 7);
        bf16x8 vf = *(const bf16x8*)&Vs[vr * 64 + vblk * 8];
        acc[f] = __builtin_amdgcn_mfma_f32_16x16x32_bf16(vf, pfr, acc[f], 0, 0, 0);
      }
    }
  }

  // epilogue: normalize, transpose O^T -> O via wave-private LDS, coalesced store
  const float inv = 1.0f / l_run;
#pragma unroll
  for (int f = 0; f < 4; ++f) {
    uint2 u;
    u.x = cvt_pk_bf16(acc[f][0] * inv, acc[f][1] * inv);
    u.y = cvt_pk_bf16(acc[f][2] * inv, acc[f][3] * inv);
    *(uint2*)&Pw[q * 64 + ((f * 16 + 4 * g) ^ psw)] = u;
  }
  const int qr = lane >> 2, c0 = (lane & 3) * 16;
  short* AOp = AO + (b * S) * D + h * 64;
#pragma unroll
  for (int r2 = 0; r2 < 2; ++r2) {
    const int cc2 = c0 + r2 * 8;
    bf16x8 ov = *(const bf16x8*)&Pw[qr * 64 + (cc2 ^ ((qr & 7) << 3))];
    *(bf16x8*)(AOp + (long)(q0 + w * 16 + qr) * D + cc2) = ov;
  }
}

// ---------------- launch ----------------

extern "C" void kernel_launch(void* const* d_in, const int* in_sizes, int n_in,
                              void* d_out, int out_size, void* d_ws, size_t ws_size,
                              hipStream_t stream) {
  const float* x = (const float*)d_in[0];
  const float* M = (const float*)d_in[1];
  const float* mask = (const float*)d_in[2];
  const float* Wq = (const float*)d_in[3];
  const float* Wk = (const float*)d_in[4];
  const float* Wv = (const float*)d_in[5];
  const float* Wo = (const float*)d_in[6];
  float* out = (float*)d_out;

  constexpr long S = 2048, D = 1024;
  constexpr long NX = 4 * S * D;  // 8388608
  constexpr long NW = D * D;      // 1048576

  short* p = (short*)d_ws;
  short* xb = p;  p += NX;
  short* wqb = p; p += NW;  // wq, wk, wv contiguous (stride NW) for batched GEMM
  short* wkb = p; p += NW;
  short* wvb = p; p += NW;
  short* wob = p; p += NW;
  short* Mtb = p; p += 4 * NW;
  short* Qb = p;  p += NX;  // Q, K, V contiguous (stride NX) for batched GEMM
  short* Kb = p;  p += NX;
  short* Vb = p;  p += NX;
  short* QMb = p; p += NX;
  short* Vtb = p; p += NX;
  int* flags = (int*)p;  p += 2048;  // 32x32 tile flags (4KB)
  short* AOb = Qb;  // Q dead after QM -> reuse for attention output

  cvt_f32_bf16<<<NX / 2048, 256, 0, stream>>>(x, xb, NX);
  cvt_f32_bf16<<<NW / 2048, 256, 0, stream>>>(Wq, wqb, NW);
  cvt_f32_bf16<<<NW / 2048, 256, 0, stream>>>(Wk, wkb, NW);
  cvt_f32_bf16<<<NW / 2048, 256, 0, stream>>>(Wv, wvb, NW);
  cvt_f32_bf16<<<NW / 2048, 256, 0, stream>>>(Wo, wob, NW);
  cvtT_M<<<dim3(16, 16, 4), 256, 0, stream>>>(M, Mtb);
  mask_flags<<<dim3(32, 32), 256, 0, stream>>>(mask, flags);

  // Q,K,V = x W{q,k,v}^T in one batched launch (A shared via sA=0)
  gemm_bt<short><<<dim3(64, 8, 3), 256, 0, stream>>>(xb, wqb, Qb, 8192, 1024, 1024,
                                                     0, NW, NX);
  // QM = Q @ M per batch (Mt is [e][d])
  gemm_bt<short><<<dim3(16, 8, 4), 256, 0, stream>>>(Qb, Mtb, QMb, 2048, 1024, 1024,
                                                     S * D, D * D, S * D);
  transposeV<<<dim3(32, 16, 4), 256, 0, stream>>>(Vb, Vtb);
  flash_attn<<<dim3(32, 16, 4), 256, 0, stream>>>(QMb, Kb, Vtb, mask, flags, AOb);
  // out = AO @ Wo^T (f32 store)
  gemm_bt<float><<<dim3(64, 8, 1), 256, 0, stream>>>(AOb, wob, out, 8192, 1024, 1024, 0, 0, 0);
}

// Round 4
// 296.480 us; speedup vs baseline: 1.3622x; 1.0522x over previous
//
#include <hip/hip_runtime.h>
#include <cstdint>

typedef __attribute__((ext_vector_type(8))) short short8;
typedef __attribute__((ext_vector_type(8))) __bf16 bf16x8;
typedef __attribute__((ext_vector_type(4))) float f32x4;

__device__ __forceinline__ short f2bf(float f) {
  union { float f; uint32_t u; } v; v.f = f;
  uint32_t u = v.u + 0x7FFFu + ((v.u >> 16) & 1u);  // RNE
  return (short)(u >> 16);
}

__device__ __forceinline__ float exp2_fast(float x) {
  return __builtin_amdgcn_exp2f(x);  // v_exp_f32 (native 2^x)
}

__device__ __forceinline__ uint32_t cvt_pk_bf16(float lo, float hi) {
  uint32_t r;
  asm("v_cvt_pk_bf16_f32 %0, %1, %2" : "=v"(r) : "v"(lo), "v"(hi));
  return r;
}

__device__ __forceinline__ void gload_lds16(const void* g, void* l) {
  __builtin_amdgcn_global_load_lds(
      (const __attribute__((address_space(1))) void*)(uintptr_t)g,
      (__attribute__((address_space(3))) void*)(uint32_t)(uintptr_t)l,
      16, 0, 0);
}

// ---------------- conversion kernels ----------------

__global__ __launch_bounds__(256) void cvt_f32_bf16(const float* __restrict__ s,
                                                    short* __restrict__ d, long n) {
  long i = ((long)blockIdx.x * 256 + threadIdx.x) * 8;
  if (i + 8 > n) return;
  const float4 a = *(const float4*)(s + i);
  const float4 b = *(const float4*)(s + i + 4);
  short8 o;
  o[0] = f2bf(a.x); o[1] = f2bf(a.y); o[2] = f2bf(a.z); o[3] = f2bf(a.w);
  o[4] = f2bf(b.x); o[5] = f2bf(b.y); o[6] = f2bf(b.z); o[7] = f2bf(b.w);
  *(short8*)(d + i) = o;
}

// Mt[z][e][d] = bf16(M[z][d][e])  (transpose-convert; also used for Wq with z=1)
__global__ __launch_bounds__(256) void cvtT_M(const float* __restrict__ Msrc,
                                              short* __restrict__ Mt) {
  __shared__ short t[64][65];
  const int tid = threadIdx.x;
  const long bofs = (long)blockIdx.z * 1024 * 1024;
  const int d0 = blockIdx.x * 64, e0 = blockIdx.y * 64;
#pragma unroll
  for (int k = 0; k < 16; ++k) {
    int idx = k * 256 + tid; int r = idx >> 6, c = idx & 63;
    t[r][c] = f2bf(Msrc[bofs + (long)(d0 + r) * 1024 + e0 + c]);
  }
  __syncthreads();
#pragma unroll
  for (int k = 0; k < 16; ++k) {
    int idx = k * 256 + tid; int r = idx >> 6, c = idx & 63;
    Mt[bofs + (long)(e0 + r) * 1024 + d0 + c] = t[c][r];
  }
}

// Vt[b][h][dh][s] = V[b][s][h*64+dh]
__global__ __launch_bounds__(256) void transposeV(const short* __restrict__ V,
                                                  short* __restrict__ Vt) {
  __shared__ short t[64][65];
  const int tid = threadIdx.x;
  const int s0 = blockIdx.x * 64, h = blockIdx.y;
  const long b = blockIdx.z;
  const short* src = V + (b * 2048) * 1024 + h * 64;
  short* dst = Vt + ((b * 16 + h) * 64) * 2048;
#pragma unroll
  for (int k = 0; k < 16; ++k) {
    int idx = k * 256 + tid; int r = idx >> 6, c = idx & 63;  // r = s row, c = dh
    t[r][c] = src[(long)(s0 + r) * 1024 + c];
  }
  __syncthreads();
#pragma unroll
  for (int k = 0; k < 16; ++k) {
    int idx = k * 256 + tid; int r = idx >> 6, c = idx & 63;  // r = dh, c = s
    dst[(long)r * 2048 + s0 + c] = t[c][r];
  }
}

// mask tile flags: flags[qt*32+tt] = any nonzero in 64x64 tile
__global__ __launch_bounds__(256) void mask_flags(const float* __restrict__ mask,
                                                  int* __restrict__ flags) {
  __shared__ int f;
  const int tid = threadIdx.x;
  if (tid == 0) f = 0;
  __syncthreads();
  const int qt = blockIdx.x, tt = blockIdx.y;
  const float* base = mask + (long)qt * 64 * 2048 + tt * 64;
  const int r = tid >> 2, c = (tid & 3) * 16;
  bool nz = false;
#pragma unroll
  for (int k = 0; k < 4; ++k) {
    float4 v = *(const float4*)(base + (long)r * 2048 + c + k * 4);
    nz = nz | (v.x != 0.f) | (v.y != 0.f) | (v.z != 0.f) | (v.w != 0.f);
  }
  if (nz) f = 1;
  __syncthreads();
  if (tid == 0) flags[qt * 32 + tt] = f;
}

// ---------------- GEMM: C[M][N] = A[M][K] * B[N][K]^T (bf16 in, f32 acc) ----------------

template <typename CT>
__global__ __launch_bounds__(256) void gemm_bt(
    const short* __restrict__ A, const short* __restrict__ B, CT* __restrict__ C,
    int M, int N, int K, long sA, long sB, long sC) {
  __shared__ __align__(16) short As[128 * 32];
  __shared__ __align__(16) short Bs[128 * 32];
  const int tid = threadIdx.x;
  const int w = tid >> 6, lane = tid & 63;
  const int wr = w >> 1, wc = w & 1;
  const short* Ab = A + (long)blockIdx.z * sA + (long)blockIdx.x * 128 * K;
  const short* Bb = B + (long)blockIdx.z * sB + (long)blockIdx.y * 128 * K;

  f32x4 acc[4][4];
#pragma unroll
  for (int i = 0; i < 4; ++i)
#pragma unroll
    for (int j = 0; j < 4; ++j) acc[i][j] = {0.f, 0.f, 0.f, 0.f};

  const int srow = lane >> 2;                      // row within 16-row chunk
  const int scol = ((lane & 3) ^ (srow & 3)) * 8;  // pre-swizzled source col (shorts)

  for (int k0 = 0; k0 < K; k0 += 32) {
    __syncthreads();
#pragma unroll
    for (int c = 0; c < 2; ++c) {
      const int chunk = w * 2 + c;
      const long gr = (long)(chunk * 16 + srow);
      gload_lds16(Ab + gr * K + k0 + scol, &As[chunk * 512]);
      gload_lds16(Bb + gr * K + k0 + scol, &Bs[chunk * 512]);
    }
    __syncthreads();
    bf16x8 af[4], bfr[4];
#pragma unroll
    for (int mf = 0; mf < 4; ++mf) {
      const int r = wr * 64 + mf * 16 + (lane & 15);
      const int cb = (lane >> 4) ^ (r & 3);
      af[mf] = *(const bf16x8*)&As[r * 32 + cb * 8];
    }
#pragma unroll
    for (int nf = 0; nf < 4; ++nf) {
      const int r = wc * 64 + nf * 16 + (lane & 15);
      const int cb = (lane >> 4) ^ (r & 3);
      bfr[nf] = *(const bf16x8*)&Bs[r * 32 + cb * 8];
    }
#pragma unroll
    for (int mf = 0; mf < 4; ++mf)
#pragma unroll
      for (int nf = 0; nf < 4; ++nf)
        acc[mf][nf] =
            __builtin_amdgcn_mfma_f32_16x16x32_bf16(af[mf], bfr[nf], acc[mf][nf], 0, 0, 0);
  }

  CT* Cb = C + (long)blockIdx.z * sC;
  const int r0 = (lane >> 4) * 4, cc = lane & 15;
#pragma unroll
  for (int mf = 0; mf < 4; ++mf)
#pragma unroll
    for (int i = 0; i < 4; ++i) {
      const long row = (long)blockIdx.x * 128 + wr * 64 + mf * 16 + r0 + i;
#pragma unroll
      for (int nf = 0; nf < 4; ++nf) {
        const long col = (long)blockIdx.y * 128 + wc * 64 + nf * 16 + cc;
        float v = acc[mf][nf][i];
        if constexpr (__is_same(CT, short))
          Cb[row * (long)N + col] = f2bf(v);
        else
          Cb[row * (long)N + col] = v;
      }
    }
}

// ---------------- flash attention (swapped QK^T, static-max softmax) ----------------
// grid: (S/64, H, B); 256 threads = 4 waves, each wave owns 16 q-rows.
// S-tile computed transposed: sacc[nf] = mfma(K, Q) -> S^T[t][q], q = lane&15.
// Softmax uses NO running max: scores are clipped to +-50 nats pre-softmax, so
// exp2(s) <= 2^72 fits f32/bf16 with full relative precision, and the scale
// cancels exactly in O = (P V)/l. P packed via v_cvt_pk_bf16_f32 into swizzled
// wave-private LDS [q][t]. PV: O^T = mfma(Vt, P). Per-lane l partials reduced
// once in the epilogue. Epilogue transposes O^T->O via LDS, coalesced stores.

__global__ __launch_bounds__(256) void flash_attn(
    const short* __restrict__ QM, const short* __restrict__ Kb,
    const short* __restrict__ Vt, const float* __restrict__ mask,
    const int* __restrict__ mflags, short* __restrict__ AO) {
  constexpr int S = 2048, D = 1024;
  constexpr float LOG2E = 1.44269504088896f;
  constexpr float C1 = 0.125f * LOG2E;   // 1/sqrt(64) * log2(e)
  constexpr float CLIP = 50.0f * LOG2E;
  __shared__ __align__(16) short Ks[64 * 64];
  __shared__ __align__(16) short Vs[64 * 64];
  __shared__ __align__(16) short Ps[4][16 * 64];
  const int tid = threadIdx.x;
  const int w = tid >> 6, lane = tid & 63;
  const int q = lane & 15, g = lane >> 4;
  const int q0 = blockIdx.x * 64;
  const int h = blockIdx.y;
  const long b = blockIdx.z;

  const short* QMb = QM + (b * S) * D + h * 64;
  const short* Kbp = Kb + (b * S) * D + h * 64;
  const short* Vtp = Vt + ((b * 16 + h) * 64) * S;
  const int* flagrow = mflags + (q0 >> 6) * 32;

  // Q fragments (B-operand): B[j=q][k], j = lane&15, k = (lane>>4)*8+reg
  bf16x8 qf[2];
#pragma unroll
  for (int ks = 0; ks < 2; ++ks)
    qf[ks] = *(const bf16x8*)(QMb + (long)(q0 + w * 16 + q) * D + ks * 32 + g * 8);

  f32x4 acc[4];  // O^T: rows d = f*16 + 4g + i, col q
#pragma unroll
  for (int f = 0; f < 4; ++f) acc[f] = {0.f, 0.f, 0.f, 0.f};
  float l_lane = 0.f;  // per-lane partial of l (this lane's t subset, this q)

  const int srow8 = lane >> 3;                       // staging row within 8-row chunk
  const int scol8 = ((lane & 7) ^ (srow8 & 7)) * 8;  // pre-swizzled source col
  short* Pw = &Ps[w][0];
  const int psw = (q & 7) << 3;  // P chunk swizzle (shorts)

  for (int t0 = 0; t0 < S; t0 += 64) {
    __syncthreads();
#pragma unroll
    for (int c = 0; c < 2; ++c) {
      const int chunk = w * 2 + c;
      const int row = chunk * 8 + srow8;
      gload_lds16(Kbp + (long)(t0 + row) * D + scol8, &Ks[chunk * 512]);
      gload_lds16(Vtp + (long)row * S + t0 + scol8, &Vs[chunk * 512]);
    }
    __syncthreads();

    // S^T tile: sacc[nf] = K Q^T, rows t = nf*16 + 4g + i, col q
    f32x4 sacc[4];
#pragma unroll
    for (int nf = 0; nf < 4; ++nf) sacc[nf] = {0.f, 0.f, 0.f, 0.f};
    __builtin_amdgcn_s_setprio(1);
#pragma unroll
    for (int ks = 0; ks < 2; ++ks) {
#pragma unroll
      for (int nf = 0; nf < 4; ++nf) {
        const int r = nf * 16 + q;
        const int blk = (ks * 4 + g) ^ (r & 7);
        bf16x8 kf = *(const bf16x8*)&Ks[r * 64 + blk * 8];
        sacc[nf] = __builtin_amdgcn_mfma_f32_16x16x32_bf16(kf, qf[ks], sacc[nf], 0, 0, 0);
      }
    }
    __builtin_amdgcn_s_setprio(0);

    // scale + clip (+ mask) in log2 domain; direct exp2 (no max subtraction)
    float pv[4][4];
    if (__builtin_expect(flagrow[t0 >> 6], 0)) {
      const float* mrow = mask + (long)(q0 + w * 16 + q) * S + t0;
#pragma unroll
      for (int nf = 0; nf < 4; ++nf) {
        float4 mv = *(const float4*)(mrow + nf * 16 + 4 * g);
        const float* mp = &mv.x;
#pragma unroll
        for (int i = 0; i < 4; ++i) {
          float s = fminf(fmaxf(sacc[nf][i] * C1, -CLIP), CLIP) + LOG2E * mp[i];
          float p = exp2_fast(s);
          l_lane += p;
          pv[nf][i] = p;
        }
      }
    } else {
#pragma unroll
      for (int nf = 0; nf < 4; ++nf)
#pragma unroll
        for (int i = 0; i < 4; ++i) {
          float p = exp2_fast(fminf(fmaxf(sacc[nf][i] * C1, -CLIP), CLIP));
          l_lane += p;
          pv[nf][i] = p;
        }
    }
#pragma unroll
    for (int nf = 0; nf < 4; ++nf) {
      uint2 u;
      u.x = cvt_pk_bf16(pv[nf][0], pv[nf][1]);
      u.y = cvt_pk_bf16(pv[nf][2], pv[nf][3]);
      *(uint2*)&Pw[q * 64 + ((nf * 16 + 4 * g) ^ psw)] = u;
    }

    // O^T += V^T P : A = Vt frag (rows d), B = P frag (j=q, k=t)
    __builtin_amdgcn_s_setprio(1);
#pragma unroll
    for (int ts = 0; ts < 2; ++ts) {
      bf16x8 pfr = *(const bf16x8*)&Pw[q * 64 + ((ts * 32 + 8 * g) ^ psw)];
#pragma unroll
      for (int f = 0; f < 4; ++f) {
        const int vr = f * 16 + q;
        const int vblk = (ts * 4 + g) ^ (vr & 7);
        bf16x8 vf = *(const bf16x8*)&Vs[vr * 64 + vblk * 8];
        acc[f] = __builtin_amdgcn_mfma_f32_16x16x32_bf16(vf, pfr, acc[f], 0, 0, 0);
      }
    }
    __builtin_amdgcn_s_setprio(0);
  }

  // epilogue: reduce l across the 4 g-groups sharing this q, normalize,
  // transpose O^T -> O via wave-private LDS, coalesced store
  float l = l_lane;
  l += __shfl_xor(l, 16);
  l += __shfl_xor(l, 32);
  const float inv = 1.0f / l;
#pragma unroll
  for (int f = 0; f < 4; ++f) {
    uint2 u;
    u.x = cvt_pk_bf16(acc[f][0] * inv, acc[f][1] * inv);
    u.y = cvt_pk_bf16(acc[f][2] * inv, acc[f][3] * inv);
    *(uint2*)&Pw[q * 64 + ((f * 16 + 4 * g) ^ psw)] = u;
  }
  const int qr = lane >> 2, c0 = (lane & 3) * 16;
  short* AOp = AO + (b * S) * D + h * 64;
#pragma unroll
  for (int r2 = 0; r2 < 2; ++r2) {
    const int cc2 = c0 + r2 * 8;
    bf16x8 ov = *(const bf16x8*)&Pw[qr * 64 + (cc2 ^ ((qr & 7) << 3))];
    *(bf16x8*)(AOp + (long)(q0 + w * 16 + qr) * D + cc2) = ov;
  }
}

// ---------------- launch ----------------

extern "C" void kernel_launch(void* const* d_in, const int* in_sizes, int n_in,
                              void* d_out, int out_size, void* d_ws, size_t ws_size,
                              hipStream_t stream) {
  const float* x = (const float*)d_in[0];
  const float* M = (const float*)d_in[1];
  const float* mask = (const float*)d_in[2];
  const float* Wq = (const float*)d_in[3];
  const float* Wk = (const float*)d_in[4];
  const float* Wv = (const float*)d_in[5];
  const float* Wo = (const float*)d_in[6];
  float* out = (float*)d_out;

  constexpr long S = 2048, D = 1024;
  constexpr long NX = 4 * S * D;  // 8388608
  constexpr long NW = D * D;      // 1048576

  short* p = (short*)d_ws;
  short* xb = p;   p += NX;
  short* wkb = p;  p += NW;  // wk, wv contiguous (stride NW) for batched K,V proj
  short* wvb = p;  p += NW;
  short* wob = p;  p += NW;
  short* wqt = p;  p += NW;       // Wq^T  [c][d]
  short* Mtb = p;  p += 4 * NW;   // M^T   [b][e][d]
  short* Gtb = p;  p += 4 * NW;   // G^T = M^T Wq  [b][e][c]
  short* Kb = p;   p += NX;       // K, V contiguous (stride NX)
  short* Vb = p;   p += NX;
  short* QMb = p;  p += NX;
  short* Vtb = p;  p += NX;
  int* flags = (int*)p;  p += 2048;  // 32x32 tile flags (4KB)
  short* AOb = Mtb;  // Mt+Gt region (8*NW == NX shorts) dead after QM -> reuse for AO

  cvt_f32_bf16<<<NX / 2048, 256, 0, stream>>>(x, xb, NX);
  cvt_f32_bf16<<<NW / 2048, 256, 0, stream>>>(Wk, wkb, NW);
  cvt_f32_bf16<<<NW / 2048, 256, 0, stream>>>(Wv, wvb, NW);
  cvt_f32_bf16<<<NW / 2048, 256, 0, stream>>>(Wo, wob, NW);
  cvtT_M<<<dim3(16, 16, 1), 256, 0, stream>>>(Wq, wqt);   // Wq^T
  cvtT_M<<<dim3(16, 16, 4), 256, 0, stream>>>(M, Mtb);    // M^T per batch
  mask_flags<<<dim3(32, 32), 256, 0, stream>>>(mask, flags);

  // K,V = x W{k,v}^T in one batched launch (A shared via sA=0)
  gemm_bt<short><<<dim3(64, 8, 2), 256, 0, stream>>>(xb, wkb, Kb, 8192, 1024, 1024,
                                                     0, NW, NX);
  // G^T[b][e][c] = sum_d Mt[b][e][d] * Wqt[c][d]  (= (Wq^T M)^T, 8.6 GF)
  gemm_bt<short><<<dim3(8, 8, 4), 256, 0, stream>>>(Mtb, wqt, Gtb, 1024, 1024, 1024,
                                                    NW, 0, NW);
  // QM[b][s][e] = sum_c x[b][s][c] * Gt[b][e][c]  (fused Q-proj + bilinear)
  gemm_bt<short><<<dim3(16, 8, 4), 256, 0, stream>>>(xb, Gtb, QMb, 2048, 1024, 1024,
                                                     S * D, NW, S * D);
  transposeV<<<dim3(32, 16, 4), 256, 0, stream>>>(Vb, Vtb);
  flash_attn<<<dim3(32, 16, 4), 256, 0, stream>>>(QMb, Kb, Vtb, mask, flags, AOb);
  // out = AO @ Wo^T (f32 store)
  gemm_bt<float><<<dim3(64, 8, 1), 256, 0, stream>>>(AOb, wob, out, 8192, 1024, 1024, 0, 0, 0);
}

// Round 5
// 284.514 us; speedup vs baseline: 1.4195x; 1.0421x over previous
//
#include <hip/hip_runtime.h>
#include <cstdint>

typedef __attribute__((ext_vector_type(8))) short short8;
typedef __attribute__((ext_vector_type(8))) __bf16 bf16x8;
typedef __attribute__((ext_vector_type(4))) float f32x4;

__device__ __forceinline__ uint32_t cvt_pk_bf16(float lo, float hi) {
  uint32_t r;
  asm("v_cvt_pk_bf16_f32 %0, %1, %2" : "=v"(r) : "v"(lo), "v"(hi));
  return r;
}

__device__ __forceinline__ short f2bf(float f) {  // 1-op RNE via cvt_pk
  return (short)cvt_pk_bf16(f, f);
}

__device__ __forceinline__ float exp2_fast(float x) {
  return __builtin_amdgcn_exp2f(x);  // v_exp_f32 (native 2^x)
}

__device__ __forceinline__ void gload_lds16(const void* g, void* l) {
  __builtin_amdgcn_global_load_lds(
      (const __attribute__((address_space(1))) void*)(uintptr_t)g,
      (__attribute__((address_space(3))) void*)(uint32_t)(uintptr_t)l,
      16, 0, 0);
}

// ---------------- conversion kernels ----------------

__global__ __launch_bounds__(256) void cvt_f32_bf16(const float* __restrict__ s,
                                                    short* __restrict__ d, long n) {
  long i = ((long)blockIdx.x * 256 + threadIdx.x) * 8;
  if (i + 8 > n) return;
  const float4 a = *(const float4*)(s + i);
  const float4 b = *(const float4*)(s + i + 4);
  uint4 o;
  o.x = cvt_pk_bf16(a.x, a.y);
  o.y = cvt_pk_bf16(a.z, a.w);
  o.z = cvt_pk_bf16(b.x, b.y);
  o.w = cvt_pk_bf16(b.z, b.w);
  *(uint4*)(d + i) = o;
}

// Mt[z][e][d] = bf16(M[z][d][e])  (transpose-convert; also used for Wq with z=1)
__global__ __launch_bounds__(256) void cvtT_M(const float* __restrict__ Msrc,
                                              short* __restrict__ Mt) {
  __shared__ short t[64][65];
  const int tid = threadIdx.x;
  const long bofs = (long)blockIdx.z * 1024 * 1024;
  const int d0 = blockIdx.x * 64, e0 = blockIdx.y * 64;
#pragma unroll
  for (int k = 0; k < 16; ++k) {
    int idx = k * 256 + tid; int r = idx >> 6, c = idx & 63;
    t[r][c] = f2bf(Msrc[bofs + (long)(d0 + r) * 1024 + e0 + c]);
  }
  __syncthreads();
#pragma unroll
  for (int k = 0; k < 16; ++k) {
    int idx = k * 256 + tid; int r = idx >> 6, c = idx & 63;
    Mt[bofs + (long)(e0 + r) * 1024 + d0 + c] = t[c][r];
  }
}

// Vt[b][h][dh][s] = V[b][s][h*64+dh]
__global__ __launch_bounds__(256) void transposeV(const short* __restrict__ V,
                                                  short* __restrict__ Vt) {
  __shared__ short t[64][65];
  const int tid = threadIdx.x;
  const int s0 = blockIdx.x * 64, h = blockIdx.y;
  const long b = blockIdx.z;
  const short* src = V + (b * 2048) * 1024 + h * 64;
  short* dst = Vt + ((b * 16 + h) * 64) * 2048;
#pragma unroll
  for (int k = 0; k < 16; ++k) {
    int idx = k * 256 + tid; int r = idx >> 6, c = idx & 63;  // r = s row, c = dh
    t[r][c] = src[(long)(s0 + r) * 1024 + c];
  }
  __syncthreads();
#pragma unroll
  for (int k = 0; k < 16; ++k) {
    int idx = k * 256 + tid; int r = idx >> 6, c = idx & 63;  // r = dh, c = s
    dst[(long)r * 2048 + s0 + c] = t[c][r];
  }
}

// mask tile flags: flags[qt*32+tt] = any nonzero in 64x64 tile
__global__ __launch_bounds__(256) void mask_flags(const float* __restrict__ mask,
                                                  int* __restrict__ flags) {
  __shared__ int f;
  const int tid = threadIdx.x;
  if (tid == 0) f = 0;
  __syncthreads();
  const int qt = blockIdx.x, tt = blockIdx.y;
  const float* base = mask + (long)qt * 64 * 2048 + tt * 64;
  const int r = tid >> 2, c = (tid & 3) * 16;
  bool nz = false;
#pragma unroll
  for (int k = 0; k < 4; ++k) {
    float4 v = *(const float4*)(base + (long)r * 2048 + c + k * 4);
    nz = nz | (v.x != 0.f) | (v.y != 0.f) | (v.z != 0.f) | (v.w != 0.f);
  }
  if (nz) f = 1;
  __syncthreads();
  if (tid == 0) flags[qt * 32 + tt] = f;
}

// ---------------- GEMM: C[M][N] = scale * A[M][K] * B[N][K]^T (bf16 in, f32 acc) ---------

template <typename CT>
__global__ __launch_bounds__(256) void gemm_bt(
    const short* __restrict__ A, const short* __restrict__ B, CT* __restrict__ C,
    int M, int N, int K, long sA, long sB, long sC, float scale) {
  __shared__ __align__(16) short As[128 * 32];
  __shared__ __align__(16) short Bs[128 * 32];
  const int tid = threadIdx.x;
  const int w = tid >> 6, lane = tid & 63;
  const int wr = w >> 1, wc = w & 1;
  const short* Ab = A + (long)blockIdx.z * sA + (long)blockIdx.x * 128 * K;
  const short* Bb = B + (long)blockIdx.z * sB + (long)blockIdx.y * 128 * K;

  f32x4 acc[4][4];
#pragma unroll
  for (int i = 0; i < 4; ++i)
#pragma unroll
    for (int j = 0; j < 4; ++j) acc[i][j] = {0.f, 0.f, 0.f, 0.f};

  const int srow = lane >> 2;                      // row within 16-row chunk
  const int scol = ((lane & 3) ^ (srow & 3)) * 8;  // pre-swizzled source col (shorts)

  for (int k0 = 0; k0 < K; k0 += 32) {
    __syncthreads();
#pragma unroll
    for (int c = 0; c < 2; ++c) {
      const int chunk = w * 2 + c;
      const long gr = (long)(chunk * 16 + srow);
      gload_lds16(Ab + gr * K + k0 + scol, &As[chunk * 512]);
      gload_lds16(Bb + gr * K + k0 + scol, &Bs[chunk * 512]);
    }
    __syncthreads();
    bf16x8 af[4], bfr[4];
#pragma unroll
    for (int mf = 0; mf < 4; ++mf) {
      const int r = wr * 64 + mf * 16 + (lane & 15);
      const int cb = (lane >> 4) ^ (r & 3);
      af[mf] = *(const bf16x8*)&As[r * 32 + cb * 8];
    }
#pragma unroll
    for (int nf = 0; nf < 4; ++nf) {
      const int r = wc * 64 + nf * 16 + (lane & 15);
      const int cb = (lane >> 4) ^ (r & 3);
      bfr[nf] = *(const bf16x8*)&Bs[r * 32 + cb * 8];
    }
#pragma unroll
    for (int mf = 0; mf < 4; ++mf)
#pragma unroll
      for (int nf = 0; nf < 4; ++nf)
        acc[mf][nf] =
            __builtin_amdgcn_mfma_f32_16x16x32_bf16(af[mf], bfr[nf], acc[mf][nf], 0, 0, 0);
  }

  CT* Cb = C + (long)blockIdx.z * sC;
  const int r0 = (lane >> 4) * 4, cc = lane & 15;
#pragma unroll
  for (int mf = 0; mf < 4; ++mf)
#pragma unroll
    for (int i = 0; i < 4; ++i) {
      const long row = (long)blockIdx.x * 128 + wr * 64 + mf * 16 + r0 + i;
#pragma unroll
      for (int nf = 0; nf < 4; ++nf) {
        const long col = (long)blockIdx.y * 128 + wc * 64 + nf * 16 + cc;
        float v = acc[mf][nf][i] * scale;
        if constexpr (__is_same(CT, short))
          Cb[row * (long)N + col] = f2bf(v);
        else
          Cb[row * (long)N + col] = v;
      }
    }
}

// ---------------- flash attention ----------------
// grid: (S/64, H, B); 256 threads = 4 waves, each wave owns 16 q-rows.
// Swapped QK^T: sacc[nf] = mfma(K, Q) -> S^T[t][q], q = lane&15. QM comes in
// pre-scaled by log2(e)/sqrt(DH), so sacc is directly in the log2 domain.
// Static-max softmax: scores clipped to +-50 nats (v_med3), exp2 <= 2^72 fits
// f32 with full relative precision; scale cancels in O = PV/l. l is computed
// on the MFMA pipe via a ones-fragment (acc_l rows all equal l).
// 2-phase pipeline: K/V double-buffered in LDS, prefetch via global_load_lds
// with counted s_waitcnt vmcnt(4) so loads stay in flight across barriers.

__global__ __launch_bounds__(256) void flash_attn(
    const short* __restrict__ QM, const short* __restrict__ Kb,
    const short* __restrict__ Vt, const float* __restrict__ mask,
    const int* __restrict__ mflags, short* __restrict__ AO) {
  constexpr int S = 2048, D = 1024, NT = S / 64;
  constexpr float LOG2E = 1.44269504088896f;
  constexpr float CLIP = 50.0f * LOG2E;
  __shared__ __align__(16) short Ks[2][64 * 64];
  __shared__ __align__(16) short Vs[2][64 * 64];
  __shared__ __align__(16) short Ps[4][16 * 64];
  const int tid = threadIdx.x;
  const int w = tid >> 6, lane = tid & 63;
  const int q = lane & 15, g = lane >> 4;
  const int q0 = blockIdx.x * 64;
  const int h = blockIdx.y;
  const long b = blockIdx.z;

  const short* QMb = QM + (b * S) * D + h * 64;
  const short* Kbp = Kb + (b * S) * D + h * 64;
  const short* Vtp = Vt + ((b * 16 + h) * 64) * S;
  const int* flagrow = mflags + (q0 >> 6) * 32;

  // Q fragments (B-operand): B[j=q][k], j = lane&15, k = (lane>>4)*8+reg
  bf16x8 qf[2];
#pragma unroll
  for (int ks = 0; ks < 2; ++ks)
    qf[ks] = *(const bf16x8*)(QMb + (long)(q0 + w * 16 + q) * D + ks * 32 + g * 8);

  bf16x8 onesf;
#pragma unroll
  for (int j = 0; j < 8; ++j) onesf[j] = (__bf16)1.0f;

  f32x4 acc[4];  // O^T: rows d = f*16 + 4g + i, col q
#pragma unroll
  for (int f = 0; f < 4; ++f) acc[f] = {0.f, 0.f, 0.f, 0.f};
  f32x4 acc_l = {0.f, 0.f, 0.f, 0.f};  // all rows = l[q]

  const int srow8 = lane >> 3;                       // staging row within 8-row chunk
  const int scol8 = ((lane & 7) ^ (srow8 & 7)) * 8;  // pre-swizzled source col
  short* Pw = &Ps[w][0];
  const int psw = (q & 7) << 3;  // P chunk swizzle (shorts)

  auto STAGE = [&](int bufi, int t0) {
#pragma unroll
    for (int c = 0; c < 2; ++c) {
      const int chunk = w * 2 + c;
      const int row = chunk * 8 + srow8;
      gload_lds16(Kbp + (long)(t0 + row) * D + scol8, &Ks[bufi][chunk * 512]);
      gload_lds16(Vtp + (long)row * S + t0 + scol8, &Vs[bufi][chunk * 512]);
    }
  };

  auto COMPUTE = [&](int bufi, int t0) {
    // S^T tile: sacc[nf] = K Q^T, rows t = nf*16 + 4g + i, col q (log2 domain)
    f32x4 sacc[4];
#pragma unroll
    for (int nf = 0; nf < 4; ++nf) sacc[nf] = {0.f, 0.f, 0.f, 0.f};
    __builtin_amdgcn_s_setprio(1);
#pragma unroll
    for (int ks = 0; ks < 2; ++ks) {
#pragma unroll
      for (int nf = 0; nf < 4; ++nf) {
        const int r = nf * 16 + q;
        const int blk = (ks * 4 + g) ^ (r & 7);
        bf16x8 kf = *(const bf16x8*)&Ks[bufi][r * 64 + blk * 8];
        sacc[nf] = __builtin_amdgcn_mfma_f32_16x16x32_bf16(kf, qf[ks], sacc[nf], 0, 0, 0);
      }
    }
    __builtin_amdgcn_s_setprio(0);

    // clip (v_med3) + optional mask + exp2; no max-tracking needed
    float pv[4][4];
    if (__builtin_expect(flagrow[t0 >> 6], 0)) {
      const float* mrow = mask + (long)(q0 + w * 16 + q) * S + t0;
#pragma unroll
      for (int nf = 0; nf < 4; ++nf) {
        float4 mv = *(const float4*)(mrow + nf * 16 + 4 * g);
        const float* mp = &mv.x;
#pragma unroll
        for (int i = 0; i < 4; ++i)
          pv[nf][i] = exp2_fast(
              __builtin_amdgcn_fmed3f(sacc[nf][i], -CLIP, CLIP) + LOG2E * mp[i]);
      }
    } else {
#pragma unroll
      for (int nf = 0; nf < 4; ++nf)
#pragma unroll
        for (int i = 0; i < 4; ++i)
          pv[nf][i] = exp2_fast(__builtin_amdgcn_fmed3f(sacc[nf][i], -CLIP, CLIP));
    }
#pragma unroll
    for (int nf = 0; nf < 4; ++nf) {
      uint2 u;
      u.x = cvt_pk_bf16(pv[nf][0], pv[nf][1]);
      u.y = cvt_pk_bf16(pv[nf][2], pv[nf][3]);
      *(uint2*)&Pw[q * 64 + ((nf * 16 + 4 * g) ^ psw)] = u;
    }

    // O^T += V^T P ; l += ones^T P (on the MFMA pipe)
    __builtin_amdgcn_s_setprio(1);
#pragma unroll
    for (int ts = 0; ts < 2; ++ts) {
      bf16x8 pfr = *(const bf16x8*)&Pw[q * 64 + ((ts * 32 + 8 * g) ^ psw)];
#pragma unroll
      for (int f = 0; f < 4; ++f) {
        const int vr = f * 16 + q;
        const int vblk = (ts * 4 + g) ^ (vr & 7);
        bf16x8 vf = *(const bf16x8*)&Vs[bufi][vr * 64 + vblk * 8];
        acc[f] = __builtin_amdgcn_mfma_f32_16x16x32_bf16(vf, pfr, acc[f], 0, 0, 0);
      }
      acc_l = __builtin_amdgcn_mfma_f32_16x16x32_bf16(onesf, pfr, acc_l, 0, 0, 0);
    }
    __builtin_amdgcn_s_setprio(0);
  };

  STAGE(0, 0);
  for (int it = 0; it < NT; ++it) {
    const int cur = it & 1;
    if (it + 1 < NT) {
      STAGE(cur ^ 1, (it + 1) * 64);
      asm volatile("s_waitcnt vmcnt(4)" ::: "memory");  // cur-buffer loads done
    } else {
      asm volatile("s_waitcnt vmcnt(0)" ::: "memory");
    }
    __builtin_amdgcn_s_barrier();
    __builtin_amdgcn_sched_barrier(0);
    COMPUTE(cur, it * 64);
    __builtin_amdgcn_sched_barrier(0);
    __builtin_amdgcn_s_barrier();
  }

  // epilogue: l = acc_l[0] (already summed over all t); normalize,
  // transpose O^T -> O via wave-private LDS, coalesced store
  const float inv = 1.0f / acc_l[0];
#pragma unroll
  for (int f = 0; f < 4; ++f) {
    uint2 u;
    u.x = cvt_pk_bf16(acc[f][0] * inv, acc[f][1] * inv);
    u.y = cvt_pk_bf16(acc[f][2] * inv, acc[f][3] * inv);
    *(uint2*)&Pw[q * 64 + ((f * 16 + 4 * g) ^ psw)] = u;
  }
  const int qr = lane >> 2, c0 = (lane & 3) * 16;
  short* AOp = AO + (b * S) * D + h * 64;
#pragma unroll
  for (int r2 = 0; r2 < 2; ++r2) {
    const int cc2 = c0 + r2 * 8;
    bf16x8 ov = *(const bf16x8*)&Pw[qr * 64 + (cc2 ^ ((qr & 7) << 3))];
    *(bf16x8*)(AOp + (long)(q0 + w * 16 + qr) * D + cc2) = ov;
  }
}

// ---------------- launch ----------------

extern "C" void kernel_launch(void* const* d_in, const int* in_sizes, int n_in,
                              void* d_out, int out_size, void* d_ws, size_t ws_size,
                              hipStream_t stream) {
  const float* x = (const float*)d_in[0];
  const float* M = (const float*)d_in[1];
  const float* mask = (const float*)d_in[2];
  const float* Wq = (const float*)d_in[3];
  const float* Wk = (const float*)d_in[4];
  const float* Wv = (const float*)d_in[5];
  const float* Wo = (const float*)d_in[6];
  float* out = (float*)d_out;

  constexpr long S = 2048, D = 1024;
  constexpr long NX = 4 * S * D;  // 8388608
  constexpr long NW = D * D;      // 1048576
  constexpr float C1 = 0.125f * 1.44269504088896f;  // 1/sqrt(64) * log2(e)

  short* p = (short*)d_ws;
  short* xb = p;   p += NX;
  short* wkb = p;  p += NW;  // wk, wv contiguous (stride NW) for batched K,V proj
  short* wvb = p;  p += NW;
  short* wob = p;  p += NW;
  short* wqt = p;  p += NW;       // Wq^T  [c][d]
  short* Mtb = p;  p += 4 * NW;   // M^T   [b][e][d]
  short* Gtb = p;  p += 4 * NW;   // G^T = M^T Wq  [b][e][c]
  short* Kb = p;   p += NX;       // K, V contiguous (stride NX)
  short* Vb = p;   p += NX;
  short* QMb = p;  p += NX;
  short* Vtb = p;  p += NX;
  int* flags = (int*)p;  p += 2048;  // 32x32 tile flags (4KB)
  short* AOb = Mtb;  // Mt+Gt region (8*NW == NX shorts) dead after QM -> reuse for AO

  cvt_f32_bf16<<<NX / 2048, 256, 0, stream>>>(x, xb, NX);
  cvt_f32_bf16<<<NW / 2048, 256, 0, stream>>>(Wk, wkb, NW);
  cvt_f32_bf16<<<NW / 2048, 256, 0, stream>>>(Wv, wvb, NW);
  cvt_f32_bf16<<<NW / 2048, 256, 0, stream>>>(Wo, wob, NW);
  cvtT_M<<<dim3(16, 16, 1), 256, 0, stream>>>(Wq, wqt);   // Wq^T
  cvtT_M<<<dim3(16, 16, 4), 256, 0, stream>>>(M, Mtb);    // M^T per batch
  mask_flags<<<dim3(32, 32), 256, 0, stream>>>(mask, flags);

  // K,V = x W{k,v}^T in one batched launch (A shared via sA=0)
  gemm_bt<short><<<dim3(64, 8, 2), 256, 0, stream>>>(xb, wkb, Kb, 8192, 1024, 1024,
                                                     0, NW, NX, 1.0f);
  // G^T[b][e][c] = sum_d Mt[b][e][d] * Wqt[c][d]  (= (Wq^T M)^T, 8.6 GF)
  gemm_bt<short><<<dim3(8, 8, 4), 256, 0, stream>>>(Mtb, wqt, Gtb, 1024, 1024, 1024,
                                                    NW, 0, NW, 1.0f);
  // QM[b][s][e] = C1 * sum_c x[b][s][c] * Gt[b][e][c]  (fused Q-proj + bilinear,
  // pre-scaled into the log2-softmax domain for flash)
  gemm_bt<short><<<dim3(16, 8, 4), 256, 0, stream>>>(xb, Gtb, QMb, 2048, 1024, 1024,
                                                     S * D, NW, S * D, C1);
  transposeV<<<dim3(32, 16, 4), 256, 0, stream>>>(Vb, Vtb);
  flash_attn<<<dim3(32, 16, 4), 256, 0, stream>>>(QMb, Kb, Vtb, mask, flags, AOb);
  // out = AO @ Wo^T (f32 store)
  gemm_bt<float><<<dim3(64, 8, 1), 256, 0, stream>>>(AOb, wob, out, 8192, 1024, 1024,
                                                     0, 0, 0, 1.0f);
}

// Round 8
// 274.364 us; speedup vs baseline: 1.4720x; 1.0370x over previous
//
#include <hip/hip_runtime.h>
#include <cstdint>

typedef __attribute__((ext_vector_type(8))) short short8;
typedef __attribute__((ext_vector_type(8))) __bf16 bf16x8;
typedef __attribute__((ext_vector_type(4))) float f32x4;

__device__ __forceinline__ uint32_t cvt_pk_bf16(float lo, float hi) {
  uint32_t r;
  asm("v_cvt_pk_bf16_f32 %0, %1, %2" : "=v"(r) : "v"(lo), "v"(hi));
  return r;
}

__device__ __forceinline__ short f2bf(float f) {  // 1-op RNE via cvt_pk
  return (short)cvt_pk_bf16(f, f);
}

__device__ __forceinline__ float exp2_fast(float x) {
  return __builtin_amdgcn_exp2f(x);  // v_exp_f32 (native 2^x)
}

// compiler-level memory fence (no instruction emitted)
__device__ __forceinline__ void mem_fence_compiler() {
  asm volatile("" ::: "memory");
}

__device__ __forceinline__ void gload_lds16(const void* g, void* l) {
  __builtin_amdgcn_global_load_lds(
      (const __attribute__((address_space(1))) void*)(uintptr_t)g,
      (__attribute__((address_space(3))) void*)(uint32_t)(uintptr_t)l,
      16, 0, 0);
}

// ---------------- conversion kernels ----------------

__global__ __launch_bounds__(256) void cvt_f32_bf16(const float* __restrict__ s,
                                                    short* __restrict__ d, long n) {
  long i = ((long)blockIdx.x * 256 + threadIdx.x) * 8;
  if (i + 8 > n) return;
  const float4 a = *(const float4*)(s + i);
  const float4 b = *(const float4*)(s + i + 4);
  uint4 o;
  o.x = cvt_pk_bf16(a.x, a.y);
  o.y = cvt_pk_bf16(a.z, a.w);
  o.z = cvt_pk_bf16(b.x, b.y);
  o.w = cvt_pk_bf16(b.z, b.w);
  *(uint4*)(d + i) = o;
}

// Mt[z][e][d] = bf16(M[z][d][e])  (transpose-convert; also used for Wq with z=1)
__global__ __launch_bounds__(256) void cvtT_M(const float* __restrict__ Msrc,
                                              short* __restrict__ Mt) {
  __shared__ short t[64][65];
  const int tid = threadIdx.x;
  const long bofs = (long)blockIdx.z * 1024 * 1024;
  const int d0 = blockIdx.x * 64, e0 = blockIdx.y * 64;
#pragma unroll
  for (int k = 0; k < 16; ++k) {
    int idx = k * 256 + tid; int r = idx >> 6, c = idx & 63;
    t[r][c] = f2bf(Msrc[bofs + (long)(d0 + r) * 1024 + e0 + c]);
  }
  __syncthreads();
#pragma unroll
  for (int k = 0; k < 16; ++k) {
    int idx = k * 256 + tid; int r = idx >> 6, c = idx & 63;
    Mt[bofs + (long)(e0 + r) * 1024 + d0 + c] = t[c][r];
  }
}

// Vt[b][h][dh][s] = V[b][s][h*64+dh]
__global__ __launch_bounds__(256) void transposeV(const short* __restrict__ V,
                                                  short* __restrict__ Vt) {
  __shared__ short t[64][65];
  const int tid = threadIdx.x;
  const int s0 = blockIdx.x * 64, h = blockIdx.y;
  const long b = blockIdx.z;
  const short* src = V + (b * 2048) * 1024 + h * 64;
  short* dst = Vt + ((b * 16 + h) * 64) * 2048;
#pragma unroll
  for (int k = 0; k < 16; ++k) {
    int idx = k * 256 + tid; int r = idx >> 6, c = idx & 63;  // r = s row, c = dh
    t[r][c] = src[(long)(s0 + r) * 1024 + c];
  }
  __syncthreads();
#pragma unroll
  for (int k = 0; k < 16; ++k) {
    int idx = k * 256 + tid; int r = idx >> 6, c = idx & 63;  // r = dh, c = s
    dst[(long)r * 2048 + s0 + c] = t[c][r];
  }
}

// mask tile flags: flags[qt*32+tt] = any nonzero in 64x64 tile
__global__ __launch_bounds__(256) void mask_flags(const float* __restrict__ mask,
                                                  int* __restrict__ flags) {
  __shared__ int f;
  const int tid = threadIdx.x;
  if (tid == 0) f = 0;
  __syncthreads();
  const int qt = blockIdx.x, tt = blockIdx.y;
  const float* base = mask + (long)qt * 64 * 2048 + tt * 64;
  const int r = tid >> 2, c = (tid & 3) * 16;
  bool nz = false;
#pragma unroll
  for (int k = 0; k < 4; ++k) {
    float4 v = *(const float4*)(base + (long)r * 2048 + c + k * 4);
    nz = nz | (v.x != 0.f) | (v.y != 0.f) | (v.z != 0.f) | (v.w != 0.f);
  }
  if (nz) f = 1;
  __syncthreads();
  if (tid == 0) flags[qt * 32 + tt] = f;
}

// ---------------- GEMM: C[M][N] = scale * A[M][K] * B[N][K]^T (bf16 in, f32 acc) ---------

template <typename CT>
__global__ __launch_bounds__(256) void gemm_bt(
    const short* __restrict__ A, const short* __restrict__ B, CT* __restrict__ C,
    int M, int N, int K, long sA, long sB, long sC, float scale) {
  __shared__ __align__(16) short As[128 * 32];
  __shared__ __align__(16) short Bs[128 * 32];
  const int tid = threadIdx.x;
  const int w = tid >> 6, lane = tid & 63;
  const int wr = w >> 1, wc = w & 1;
  const short* Ab = A + (long)blockIdx.z * sA + (long)blockIdx.x * 128 * K;
  const short* Bb = B + (long)blockIdx.z * sB + (long)blockIdx.y * 128 * K;

  f32x4 acc[4][4];
#pragma unroll
  for (int i = 0; i < 4; ++i)
#pragma unroll
    for (int j = 0; j < 4; ++j) acc[i][j] = {0.f, 0.f, 0.f, 0.f};

  const int srow = lane >> 2;                      // row within 16-row chunk
  const int scol = ((lane & 3) ^ (srow & 3)) * 8;  // pre-swizzled source col (shorts)

  for (int k0 = 0; k0 < K; k0 += 32) {
    __syncthreads();
#pragma unroll
    for (int c = 0; c < 2; ++c) {
      const int chunk = w * 2 + c;
      const long gr = (long)(chunk * 16 + srow);
      gload_lds16(Ab + gr * K + k0 + scol, &As[chunk * 512]);
      gload_lds16(Bb + gr * K + k0 + scol, &Bs[chunk * 512]);
    }
    __syncthreads();
    bf16x8 af[4], bfr[4];
#pragma unroll
    for (int mf = 0; mf < 4; ++mf) {
      const int r = wr * 64 + mf * 16 + (lane & 15);
      const int cb = (lane >> 4) ^ (r & 3);
      af[mf] = *(const bf16x8*)&As[r * 32 + cb * 8];
    }
#pragma unroll
    for (int nf = 0; nf < 4; ++nf) {
      const int r = wc * 64 + nf * 16 + (lane & 15);
      const int cb = (lane >> 4) ^ (r & 3);
      bfr[nf] = *(const bf16x8*)&Bs[r * 32 + cb * 8];
    }
#pragma unroll
    for (int mf = 0; mf < 4; ++mf)
#pragma unroll
      for (int nf = 0; nf < 4; ++nf)
        acc[mf][nf] =
            __builtin_amdgcn_mfma_f32_16x16x32_bf16(af[mf], bfr[nf], acc[mf][nf], 0, 0, 0);
  }

  CT* Cb = C + (long)blockIdx.z * sC;
  const int r0 = (lane >> 4) * 4, cc = lane & 15;
#pragma unroll
  for (int mf = 0; mf < 4; ++mf)
#pragma unroll
    for (int i = 0; i < 4; ++i) {
      const long row = (long)blockIdx.x * 128 + wr * 64 + mf * 16 + r0 + i;
#pragma unroll
      for (int nf = 0; nf < 4; ++nf) {
        const long col = (long)blockIdx.y * 128 + wc * 64 + nf * 16 + cc;
        float v = acc[mf][nf][i] * scale;
        if constexpr (__is_same(CT, short))
          Cb[row * (long)N + col] = f2bf(v);
        else
          Cb[row * (long)N + col] = v;
      }
    }
}

// ---------------- flash attention ----------------
// grid: (S/128, H, B); 512 threads = 8 waves; block covers 128 q-rows, each
// wave owns 16 q-rows. Per-wave compute path is IDENTICAL to the verified
// round-5 kernel (VGPR ~64); the 8-wave block just shares each staged 64x64
// K/V tile across 2x the work (staging + barrier cost per unit work halves)
// and raises occupancy (48KB LDS -> 3 blocks/CU -> 24 waves/CU).
// Swapped QK^T: sacc[nf] = mfma(K, Q) -> S^T[t][q] (log2 domain; QM comes in
// pre-scaled by log2(e)/sqrt(DH)). Static-max softmax: scores clipped to
// +-50 nats (v_med3), exp2 <= 2^72 fits f32; scale cancels in O = PV/l.
// l computed on the MFMA pipe via a ones-fragment. 2-phase pipeline: K/V
// double-buffered, counted s_waitcnt vmcnt(2) keeps prefetch in flight
// (each wave stages ONE 8-row chunk of K and V: 2 loads per tile).

__global__ __launch_bounds__(512) void flash_attn(
    const short* __restrict__ QM, const short* __restrict__ Kb,
    const short* __restrict__ Vt, const float* __restrict__ mask,
    const int* __restrict__ mflags, short* __restrict__ AO) {
  constexpr int S = 2048, D = 1024, NT = S / 64;
  constexpr float LOG2E = 1.44269504088896f;
  constexpr float CLIP = 50.0f * LOG2E;
  __shared__ __align__(16) short Ks[2][64 * 64];
  __shared__ __align__(16) short Vs[2][64 * 64];
  __shared__ __align__(16) short Ps[8][16 * 64];
  const int tid = threadIdx.x;
  const int w = tid >> 6, lane = tid & 63;
  const int q = lane & 15, g = lane >> 4;
  const int q0 = blockIdx.x * 128;
  const int h = blockIdx.y;
  const long b = blockIdx.z;

  const short* QMb = QM + (b * S) * D + h * 64;
  const short* Kbp = Kb + (b * S) * D + h * 64;
  const short* Vtp = Vt + ((b * 16 + h) * 64) * S;
  const int* flagrow = mflags + ((q0 + w * 16) >> 6) * 32;

  // Q fragments (B-operand): B[j=q][k], j = lane&15, k = (lane>>4)*8+reg
  bf16x8 qf[2];
#pragma unroll
  for (int ks = 0; ks < 2; ++ks)
    qf[ks] = *(const bf16x8*)(QMb + (long)(q0 + w * 16 + q) * D + ks * 32 + g * 8);

  bf16x8 onesf;
#pragma unroll
  for (int j = 0; j < 8; ++j) onesf[j] = (__bf16)1.0f;

  f32x4 acc[4];  // O^T: rows d = f*16 + 4g + i, col q
#pragma unroll
  for (int f = 0; f < 4; ++f) acc[f] = {0.f, 0.f, 0.f, 0.f};
  f32x4 acc_l = {0.f, 0.f, 0.f, 0.f};  // all rows = l[q]

  const int srow8 = lane >> 3;                       // staging row within 8-row chunk
  const int scol8 = ((lane & 7) ^ (srow8 & 7)) * 8;  // pre-swizzled source col
  short* Pw = &Ps[w][0];
  const int psw = (q & 7) << 3;  // P chunk swizzle (shorts)

  auto STAGE = [&](int bufi, int t0) {
    // 8 waves x 1 chunk: wave w stages rows w*8..w*8+7 of K and V^T tiles
    const int row = w * 8 + srow8;
    gload_lds16(Kbp + (long)(t0 + row) * D + scol8, &Ks[bufi][w * 512]);
    gload_lds16(Vtp + (long)row * S + t0 + scol8, &Vs[bufi][w * 512]);
  };

  auto COMPUTE = [&](int bufi, int t0) {
    // S^T tile: sacc[nf] = K Q^T, rows t = nf*16 + 4g + i, col q (log2 domain)
    f32x4 sacc[4];
#pragma unroll
    for (int nf = 0; nf < 4; ++nf) sacc[nf] = {0.f, 0.f, 0.f, 0.f};
    __builtin_amdgcn_s_setprio(1);
#pragma unroll
    for (int ks = 0; ks < 2; ++ks) {
#pragma unroll
      for (int nf = 0; nf < 4; ++nf) {
        const int r = nf * 16 + q;
        const int blk = (ks * 4 + g) ^ (r & 7);
        bf16x8 kf = *(const bf16x8*)&Ks[bufi][r * 64 + blk * 8];
        sacc[nf] = __builtin_amdgcn_mfma_f32_16x16x32_bf16(kf, qf[ks], sacc[nf], 0, 0, 0);
      }
    }
    __builtin_amdgcn_s_setprio(0);

    // clip (v_med3) + optional mask + exp2; no max-tracking needed
    float pv[4][4];
    if (__builtin_expect(flagrow[t0 >> 6], 0)) {
      const float* mrow = mask + (long)(q0 + w * 16 + q) * S + t0;
#pragma unroll
      for (int nf = 0; nf < 4; ++nf) {
        float4 mv = *(const float4*)(mrow + nf * 16 + 4 * g);
        const float* mp = &mv.x;
#pragma unroll
        for (int i = 0; i < 4; ++i)
          pv[nf][i] = exp2_fast(
              __builtin_amdgcn_fmed3f(sacc[nf][i], -CLIP, CLIP) + LOG2E * mp[i]);
      }
    } else {
#pragma unroll
      for (int nf = 0; nf < 4; ++nf)
#pragma unroll
        for (int i = 0; i < 4; ++i)
          pv[nf][i] = exp2_fast(__builtin_amdgcn_fmed3f(sacc[nf][i], -CLIP, CLIP));
    }
#pragma unroll
    for (int nf = 0; nf < 4; ++nf) {
      uint2 u;
      u.x = cvt_pk_bf16(pv[nf][0], pv[nf][1]);
      u.y = cvt_pk_bf16(pv[nf][2], pv[nf][3]);
      *(uint2*)&Pw[q * 64 + ((nf * 16 + 4 * g) ^ psw)] = u;
    }

    mem_fence_compiler();  // P stores (uint2) precede P loads (bf16x8)

    // O^T += V^T P ; l += ones^T P (on the MFMA pipe)
    __builtin_amdgcn_s_setprio(1);
#pragma unroll
    for (int ts = 0; ts < 2; ++ts) {
      bf16x8 pfr = *(const bf16x8*)&Pw[q * 64 + ((ts * 32 + 8 * g) ^ psw)];
#pragma unroll
      for (int f = 0; f < 4; ++f) {
        const int vr = f * 16 + q;
        const int vblk = (ts * 4 + g) ^ (vr & 7);
        bf16x8 vf = *(const bf16x8*)&Vs[bufi][vr * 64 + vblk * 8];
        acc[f] = __builtin_amdgcn_mfma_f32_16x16x32_bf16(vf, pfr, acc[f], 0, 0, 0);
      }
      acc_l = __builtin_amdgcn_mfma_f32_16x16x32_bf16(onesf, pfr, acc_l, 0, 0, 0);
    }
    __builtin_amdgcn_s_setprio(0);
    mem_fence_compiler();  // P loads precede next tile's P stores
  };

  STAGE(0, 0);
  for (int it = 0; it < NT; ++it) {
    const int cur = it & 1;
    if (it + 1 < NT) {
      STAGE(cur ^ 1, (it + 1) * 64);
      asm volatile("s_waitcnt vmcnt(2)" ::: "memory");  // cur-buffer loads done
    } else {
      asm volatile("s_waitcnt vmcnt(0)" ::: "memory");
    }
    __builtin_amdgcn_s_barrier();
    __builtin_amdgcn_sched_barrier(0);
    COMPUTE(cur, it * 64);
    __builtin_amdgcn_sched_barrier(0);
    __builtin_amdgcn_s_barrier();
  }

  // epilogue: l = acc_l[0] (already summed over all t); normalize,
  // transpose O^T -> O via wave-private LDS, coalesced store
  const float inv = 1.0f / acc_l[0];
#pragma unroll
  for (int f = 0; f < 4; ++f) {
    uint2 u;
    u.x = cvt_pk_bf16(acc[f][0] * inv, acc[f][1] * inv);
    u.y = cvt_pk_bf16(acc[f][2] * inv, acc[f][3] * inv);
    *(uint2*)&Pw[q * 64 + ((f * 16 + 4 * g) ^ psw)] = u;
  }
  mem_fence_compiler();  // O stores (uint2) precede transpose loads (bf16x8)
  const int qr = lane >> 2, c0 = (lane & 3) * 16;
  short* AOp = AO + (b * S) * D + h * 64;
#pragma unroll
  for (int r2 = 0; r2 < 2; ++r2) {
    const int cc2 = c0 + r2 * 8;
    bf16x8 ov = *(const bf16x8*)&Pw[qr * 64 + (cc2 ^ ((qr & 7) << 3))];
    *(bf16x8*)(AOp + (long)(q0 + w * 16 + qr) * D + cc2) = ov;
  }
}

// ---------------- launch ----------------

extern "C" void kernel_launch(void* const* d_in, const int* in_sizes, int n_in,
                              void* d_out, int out_size, void* d_ws, size_t ws_size,
                              hipStream_t stream) {
  const float* x = (const float*)d_in[0];
  const float* M = (const float*)d_in[1];
  const float* mask = (const float*)d_in[2];
  const float* Wq = (const float*)d_in[3];
  const float* Wk = (const float*)d_in[4];
  const float* Wv = (const float*)d_in[5];
  const float* Wo = (const float*)d_in[6];
  float* out = (float*)d_out;

  constexpr long S = 2048, D = 1024;
  constexpr long NX = 4 * S * D;  // 8388608
  constexpr long NW = D * D;      // 1048576
  constexpr float C1 = 0.125f * 1.44269504088896f;  // 1/sqrt(64) * log2(e)

  short* p = (short*)d_ws;
  short* xb = p;   p += NX;
  short* wkb = p;  p += NW;  // wk, wv contiguous (stride NW) for batched K,V proj
  short* wvb = p;  p += NW;
  short* wob = p;  p += NW;
  short* wqt = p;  p += NW;       // Wq^T  [c][d]
  short* Mtb = p;  p += 4 * NW;   // M^T   [b][e][d]
  short* Gtb = p;  p += 4 * NW;   // G^T = M^T Wq  [b][e][c]
  short* Kb = p;   p += NX;       // K, V contiguous (stride NX)
  short* Vb = p;   p += NX;
  short* QMb = p;  p += NX;
  short* Vtb = p;  p += NX;
  int* flags = (int*)p;  p += 2048;  // 32x32 tile flags (4KB)
  short* AOb = Mtb;  // Mt+Gt region (8*NW == NX shorts) dead after QM -> reuse for AO

  cvt_f32_bf16<<<NX / 2048, 256, 0, stream>>>(x, xb, NX);
  cvt_f32_bf16<<<NW / 2048, 256, 0, stream>>>(Wk, wkb, NW);
  cvt_f32_bf16<<<NW / 2048, 256, 0, stream>>>(Wv, wvb, NW);
  cvt_f32_bf16<<<NW / 2048, 256, 0, stream>>>(Wo, wob, NW);
  cvtT_M<<<dim3(16, 16, 1), 256, 0, stream>>>(Wq, wqt);   // Wq^T
  cvtT_M<<<dim3(16, 16, 4), 256, 0, stream>>>(M, Mtb);    // M^T per batch
  mask_flags<<<dim3(32, 32), 256, 0, stream>>>(mask, flags);

  // K,V = x W{k,v}^T in one batched launch (A shared via sA=0)
  gemm_bt<short><<<dim3(64, 8, 2), 256, 0, stream>>>(xb, wkb, Kb, 8192, 1024, 1024,
                                                     0, NW, NX, 1.0f);
  // G^T[b][e][c] = sum_d Mt[b][e][d] * Wqt[c][d]  (= (Wq^T M)^T, 8.6 GF)
  gemm_bt<short><<<dim3(8, 8, 4), 256, 0, stream>>>(Mtb, wqt, Gtb, 1024, 1024, 1024,
                                                    NW, 0, NW, 1.0f);
  // QM[b][s][e] = C1 * sum_c x[b][s][c] * Gt[b][e][c]  (fused Q-proj + bilinear,
  // pre-scaled into the log2-softmax domain for flash)
  gemm_bt<short><<<dim3(16, 8, 4), 256, 0, stream>>>(xb, Gtb, QMb, 2048, 1024, 1024,
                                                     S * D, NW, S * D, C1);
  transposeV<<<dim3(32, 16, 4), 256, 0, stream>>>(Vb, Vtb);
  flash_attn<<<dim3(16, 16, 4), 512, 0, stream>>>(QMb, Kb, Vtb, mask, flags, AOb);
  // out = AO @ Wo^T (f32 store)
  gemm_bt<float><<<dim3(64, 8, 1), 256, 0, stream>>>(AOb, wob, out, 8192, 1024, 1024,
                                                     0, 0, 0, 1.0f);
}

// Round 9
// 259.933 us; speedup vs baseline: 1.5537x; 1.0555x over previous
//
#include <hip/hip_runtime.h>
#include <cstdint>

typedef __attribute__((ext_vector_type(8))) short short8;
typedef __attribute__((ext_vector_type(8))) __bf16 bf16x8;
typedef __attribute__((ext_vector_type(4))) float f32x4;

__device__ __forceinline__ uint32_t cvt_pk_bf16(float lo, float hi) {
  uint32_t r;
  asm("v_cvt_pk_bf16_f32 %0, %1, %2" : "=v"(r) : "v"(lo), "v"(hi));
  return r;
}

__device__ __forceinline__ short f2bf(float f) {  // 1-op RNE via cvt_pk
  return (short)cvt_pk_bf16(f, f);
}

__device__ __forceinline__ float exp2_fast(float x) {
  return __builtin_amdgcn_exp2f(x);  // v_exp_f32 (native 2^x)
}

// compiler-level memory fence (no instruction emitted)
__device__ __forceinline__ void mem_fence_compiler() {
  asm volatile("" ::: "memory");
}

__device__ __forceinline__ void gload_lds16(const void* g, void* l) {
  __builtin_amdgcn_global_load_lds(
      (const __attribute__((address_space(1))) void*)(uintptr_t)g,
      (__attribute__((address_space(3))) void*)(uint32_t)(uintptr_t)l,
      16, 0, 0);
}

// ---------------- conversion kernels ----------------

__global__ __launch_bounds__(256) void cvt_f32_bf16(const float* __restrict__ s,
                                                    short* __restrict__ d, long n) {
  long i = ((long)blockIdx.x * 256 + threadIdx.x) * 8;
  if (i + 8 > n) return;
  const float4 a = *(const float4*)(s + i);
  const float4 b = *(const float4*)(s + i + 4);
  uint4 o;
  o.x = cvt_pk_bf16(a.x, a.y);
  o.y = cvt_pk_bf16(a.z, a.w);
  o.z = cvt_pk_bf16(b.x, b.y);
  o.w = cvt_pk_bf16(b.z, b.w);
  *(uint4*)(d + i) = o;
}

// Mt[z][e][d] = bf16(M[z][d][e])  (transpose-convert; also used for Wq with z=1)
__global__ __launch_bounds__(256) void cvtT_M(const float* __restrict__ Msrc,
                                              short* __restrict__ Mt) {
  __shared__ short t[64][65];
  const int tid = threadIdx.x;
  const long bofs = (long)blockIdx.z * 1024 * 1024;
  const int d0 = blockIdx.x * 64, e0 = blockIdx.y * 64;
#pragma unroll
  for (int k = 0; k < 16; ++k) {
    int idx = k * 256 + tid; int r = idx >> 6, c = idx & 63;
    t[r][c] = f2bf(Msrc[bofs + (long)(d0 + r) * 1024 + e0 + c]);
  }
  __syncthreads();
#pragma unroll
  for (int k = 0; k < 16; ++k) {
    int idx = k * 256 + tid; int r = idx >> 6, c = idx & 63;
    Mt[bofs + (long)(e0 + r) * 1024 + d0 + c] = t[c][r];
  }
}

// Vt[b][h][dh][s] = V[b][s][h*64+dh]
__global__ __launch_bounds__(256) void transposeV(const short* __restrict__ V,
                                                  short* __restrict__ Vt) {
  __shared__ short t[64][65];
  const int tid = threadIdx.x;
  const int s0 = blockIdx.x * 64, h = blockIdx.y;
  const long b = blockIdx.z;
  const short* src = V + (b * 2048) * 1024 + h * 64;
  short* dst = Vt + ((b * 16 + h) * 64) * 2048;
#pragma unroll
  for (int k = 0; k < 16; ++k) {
    int idx = k * 256 + tid; int r = idx >> 6, c = idx & 63;  // r = s row, c = dh
    t[r][c] = src[(long)(s0 + r) * 1024 + c];
  }
  __syncthreads();
#pragma unroll
  for (int k = 0; k < 16; ++k) {
    int idx = k * 256 + tid; int r = idx >> 6, c = idx & 63;  // r = dh, c = s
    dst[(long)r * 2048 + s0 + c] = t[c][r];
  }
}

// mask tile flags: flags[qt*32+tt] = any nonzero in 64x64 tile
__global__ __launch_bounds__(256) void mask_flags(const float* __restrict__ mask,
                                                  int* __restrict__ flags) {
  __shared__ int f;
  const int tid = threadIdx.x;
  if (tid == 0) f = 0;
  __syncthreads();
  const int qt = blockIdx.x, tt = blockIdx.y;
  const float* base = mask + (long)qt * 64 * 2048 + tt * 64;
  const int r = tid >> 2, c = (tid & 3) * 16;
  bool nz = false;
#pragma unroll
  for (int k = 0; k < 4; ++k) {
    float4 v = *(const float4*)(base + (long)r * 2048 + c + k * 4);
    nz = nz | (v.x != 0.f) | (v.y != 0.f) | (v.z != 0.f) | (v.w != 0.f);
  }
  if (nz) f = 1;
  __syncthreads();
  if (tid == 0) flags[qt * 32 + tt] = f;
}

// ---------------- GEMM: C[M][N] = scale * A[M][K] * B[N][K]^T (bf16 in, f32 acc) ---------
// 128x128 tile, BK=64 (m97 config): 16 K-iterations for K=1024, 32 MFMA per
// barrier pair. Staging uses the flash-verified 64-wide-tile XOR swizzle
// (pre-swizzled global source + swizzled ds_read) - conflict-free b128 reads.

template <typename CT>
__global__ __launch_bounds__(256) void gemm_bt(
    const short* __restrict__ A, const short* __restrict__ B, CT* __restrict__ C,
    int M, int N, int K, long sA, long sB, long sC, float scale) {
  __shared__ __align__(16) short As[128 * 64];
  __shared__ __align__(16) short Bs[128 * 64];
  const int tid = threadIdx.x;
  const int w = tid >> 6, lane = tid & 63;
  const int wr = w >> 1, wc = w & 1;
  const int g = lane >> 4;
  const short* Ab = A + (long)blockIdx.z * sA + (long)blockIdx.x * 128 * K;
  const short* Bb = B + (long)blockIdx.z * sB + (long)blockIdx.y * 128 * K;

  f32x4 acc[4][4];
#pragma unroll
  for (int i = 0; i < 4; ++i)
#pragma unroll
    for (int j = 0; j < 4; ++j) acc[i][j] = {0.f, 0.f, 0.f, 0.f};

  const int srow8 = lane >> 3;                       // row within 8-row chunk
  const int scol8 = ((lane & 7) ^ (srow8 & 7)) * 8;  // pre-swizzled source col (shorts)

  for (int k0 = 0; k0 < K; k0 += 64) {
    __syncthreads();
    // 16 chunks of 8 rows per matrix; wave w stages chunks {c*4+w}
#pragma unroll
    for (int c = 0; c < 4; ++c) {
      const int chunk = c * 4 + w;
      const long row = chunk * 8 + srow8;
      gload_lds16(Ab + row * K + k0 + scol8, &As[chunk * 512]);
      gload_lds16(Bb + row * K + k0 + scol8, &Bs[chunk * 512]);
    }
    __syncthreads();
#pragma unroll
    for (int s = 0; s < 2; ++s) {  // two k-slices of 32 within the BK=64 tile
      bf16x8 af[4], bfr[4];
#pragma unroll
      for (int mf = 0; mf < 4; ++mf) {
        const int r = wr * 64 + mf * 16 + (lane & 15);
        const int cb = (s * 4 + g) ^ (r & 7);
        af[mf] = *(const bf16x8*)&As[r * 64 + cb * 8];
      }
#pragma unroll
      for (int nf = 0; nf < 4; ++nf) {
        const int r = wc * 64 + nf * 16 + (lane & 15);
        const int cb = (s * 4 + g) ^ (r & 7);
        bfr[nf] = *(const bf16x8*)&Bs[r * 64 + cb * 8];
      }
#pragma unroll
      for (int mf = 0; mf < 4; ++mf)
#pragma unroll
        for (int nf = 0; nf < 4; ++nf)
          acc[mf][nf] =
              __builtin_amdgcn_mfma_f32_16x16x32_bf16(af[mf], bfr[nf], acc[mf][nf], 0, 0, 0);
    }
  }

  CT* Cb = C + (long)blockIdx.z * sC;
  const int r0 = g * 4, cc = lane & 15;
#pragma unroll
  for (int mf = 0; mf < 4; ++mf)
#pragma unroll
    for (int i = 0; i < 4; ++i) {
      const long row = (long)blockIdx.x * 128 + wr * 64 + mf * 16 + r0 + i;
#pragma unroll
      for (int nf = 0; nf < 4; ++nf) {
        const long col = (long)blockIdx.y * 128 + wc * 64 + nf * 16 + cc;
        float v = acc[mf][nf][i] * scale;
        if constexpr (__is_same(CT, short))
          Cb[row * (long)N + col] = f2bf(v);
        else
          Cb[row * (long)N + col] = v;
      }
    }
}

// ---------------- flash attention (UNCHANGED from verified round-8 kernel) ----------------
// grid: (S/128, H, B); 512 threads = 8 waves; block covers 128 q-rows, each
// wave owns 16 q-rows. Swapped QK^T -> S^T[t][q]; static-max log2-domain
// softmax (scores pre-scaled, clipped +-50 nats via v_med3); l on the MFMA
// pipe via ones-fragment; K/V double-buffered with counted vmcnt(2).

__global__ __launch_bounds__(512) void flash_attn(
    const short* __restrict__ QM, const short* __restrict__ Kb,
    const short* __restrict__ Vt, const float* __restrict__ mask,
    const int* __restrict__ mflags, short* __restrict__ AO) {
  constexpr int S = 2048, D = 1024, NT = S / 64;
  constexpr float LOG2E = 1.44269504088896f;
  constexpr float CLIP = 50.0f * LOG2E;
  __shared__ __align__(16) short Ks[2][64 * 64];
  __shared__ __align__(16) short Vs[2][64 * 64];
  __shared__ __align__(16) short Ps[8][16 * 64];
  const int tid = threadIdx.x;
  const int w = tid >> 6, lane = tid & 63;
  const int q = lane & 15, g = lane >> 4;
  const int q0 = blockIdx.x * 128;
  const int h = blockIdx.y;
  const long b = blockIdx.z;

  const short* QMb = QM + (b * S) * D + h * 64;
  const short* Kbp = Kb + (b * S) * D + h * 64;
  const short* Vtp = Vt + ((b * 16 + h) * 64) * S;
  const int* flagrow = mflags + ((q0 + w * 16) >> 6) * 32;

  bf16x8 qf[2];
#pragma unroll
  for (int ks = 0; ks < 2; ++ks)
    qf[ks] = *(const bf16x8*)(QMb + (long)(q0 + w * 16 + q) * D + ks * 32 + g * 8);

  bf16x8 onesf;
#pragma unroll
  for (int j = 0; j < 8; ++j) onesf[j] = (__bf16)1.0f;

  f32x4 acc[4];
#pragma unroll
  for (int f = 0; f < 4; ++f) acc[f] = {0.f, 0.f, 0.f, 0.f};
  f32x4 acc_l = {0.f, 0.f, 0.f, 0.f};

  const int srow8 = lane >> 3;
  const int scol8 = ((lane & 7) ^ (srow8 & 7)) * 8;
  short* Pw = &Ps[w][0];
  const int psw = (q & 7) << 3;

  auto STAGE = [&](int bufi, int t0) {
    const int row = w * 8 + srow8;
    gload_lds16(Kbp + (long)(t0 + row) * D + scol8, &Ks[bufi][w * 512]);
    gload_lds16(Vtp + (long)row * S + t0 + scol8, &Vs[bufi][w * 512]);
  };

  auto COMPUTE = [&](int bufi, int t0) {
    f32x4 sacc[4];
#pragma unroll
    for (int nf = 0; nf < 4; ++nf) sacc[nf] = {0.f, 0.f, 0.f, 0.f};
    __builtin_amdgcn_s_setprio(1);
#pragma unroll
    for (int ks = 0; ks < 2; ++ks) {
#pragma unroll
      for (int nf = 0; nf < 4; ++nf) {
        const int r = nf * 16 + q;
        const int blk = (ks * 4 + g) ^ (r & 7);
        bf16x8 kf = *(const bf16x8*)&Ks[bufi][r * 64 + blk * 8];
        sacc[nf] = __builtin_amdgcn_mfma_f32_16x16x32_bf16(kf, qf[ks], sacc[nf], 0, 0, 0);
      }
    }
    __builtin_amdgcn_s_setprio(0);

    float pv[4][4];
    if (__builtin_expect(flagrow[t0 >> 6], 0)) {
      const float* mrow = mask + (long)(q0 + w * 16 + q) * S + t0;
#pragma unroll
      for (int nf = 0; nf < 4; ++nf) {
        float4 mv = *(const float4*)(mrow + nf * 16 + 4 * g);
        const float* mp = &mv.x;
#pragma unroll
        for (int i = 0; i < 4; ++i)
          pv[nf][i] = exp2_fast(
              __builtin_amdgcn_fmed3f(sacc[nf][i], -CLIP, CLIP) + LOG2E * mp[i]);
      }
    } else {
#pragma unroll
      for (int nf = 0; nf < 4; ++nf)
#pragma unroll
        for (int i = 0; i < 4; ++i)
          pv[nf][i] = exp2_fast(__builtin_amdgcn_fmed3f(sacc[nf][i], -CLIP, CLIP));
    }
#pragma unroll
    for (int nf = 0; nf < 4; ++nf) {
      uint2 u;
      u.x = cvt_pk_bf16(pv[nf][0], pv[nf][1]);
      u.y = cvt_pk_bf16(pv[nf][2], pv[nf][3]);
      *(uint2*)&Pw[q * 64 + ((nf * 16 + 4 * g) ^ psw)] = u;
    }

    mem_fence_compiler();

    __builtin_amdgcn_s_setprio(1);
#pragma unroll
    for (int ts = 0; ts < 2; ++ts) {
      bf16x8 pfr = *(const bf16x8*)&Pw[q * 64 + ((ts * 32 + 8 * g) ^ psw)];
#pragma unroll
      for (int f = 0; f < 4; ++f) {
        const int vr = f * 16 + q;
        const int vblk = (ts * 4 + g) ^ (vr & 7);
        bf16x8 vf = *(const bf16x8*)&Vs[bufi][vr * 64 + vblk * 8];
        acc[f] = __builtin_amdgcn_mfma_f32_16x16x32_bf16(vf, pfr, acc[f], 0, 0, 0);
      }
      acc_l = __builtin_amdgcn_mfma_f32_16x16x32_bf16(onesf, pfr, acc_l, 0, 0, 0);
    }
    __builtin_amdgcn_s_setprio(0);
    mem_fence_compiler();
  };

  STAGE(0, 0);
  for (int it = 0; it < NT; ++it) {
    const int cur = it & 1;
    if (it + 1 < NT) {
      STAGE(cur ^ 1, (it + 1) * 64);
      asm volatile("s_waitcnt vmcnt(2)" ::: "memory");
    } else {
      asm volatile("s_waitcnt vmcnt(0)" ::: "memory");
    }
    __builtin_amdgcn_s_barrier();
    __builtin_amdgcn_sched_barrier(0);
    COMPUTE(cur, it * 64);
    __builtin_amdgcn_sched_barrier(0);
    __builtin_amdgcn_s_barrier();
  }

  const float inv = 1.0f / acc_l[0];
#pragma unroll
  for (int f = 0; f < 4; ++f) {
    uint2 u;
    u.x = cvt_pk_bf16(acc[f][0] * inv, acc[f][1] * inv);
    u.y = cvt_pk_bf16(acc[f][2] * inv, acc[f][3] * inv);
    *(uint2*)&Pw[q * 64 + ((f * 16 + 4 * g) ^ psw)] = u;
  }
  mem_fence_compiler();
  const int qr = lane >> 2, c0 = (lane & 3) * 16;
  short* AOp = AO + (b * S) * D + h * 64;
#pragma unroll
  for (int r2 = 0; r2 < 2; ++r2) {
    const int cc2 = c0 + r2 * 8;
    bf16x8 ov = *(const bf16x8*)&Pw[qr * 64 + (cc2 ^ ((qr & 7) << 3))];
    *(bf16x8*)(AOp + (long)(q0 + w * 16 + qr) * D + cc2) = ov;
  }
}

// ---------------- launch ----------------

extern "C" void kernel_launch(void* const* d_in, const int* in_sizes, int n_in,
                              void* d_out, int out_size, void* d_ws, size_t ws_size,
                              hipStream_t stream) {
  const float* x = (const float*)d_in[0];
  const float* M = (const float*)d_in[1];
  const float* mask = (const float*)d_in[2];
  const float* Wq = (const float*)d_in[3];
  const float* Wk = (const float*)d_in[4];
  const float* Wv = (const float*)d_in[5];
  const float* Wo = (const float*)d_in[6];
  float* out = (float*)d_out;

  constexpr long S = 2048, D = 1024;
  constexpr long NX = 4 * S * D;  // 8388608
  constexpr long NW = D * D;      // 1048576
  constexpr float C1 = 0.125f * 1.44269504088896f;  // 1/sqrt(64) * log2(e)

  short* p = (short*)d_ws;
  short* xb = p;   p += NX;
  short* wkb = p;  p += NW;  // wk, wv contiguous (stride NW) for batched K,V proj
  short* wvb = p;  p += NW;
  short* wob = p;  p += NW;
  short* wqt = p;  p += NW;       // Wq^T  [c][d]
  short* Mtb = p;  p += 4 * NW;   // M^T   [b][e][d]
  short* Gtb = p;  p += 4 * NW;   // G^T = M^T Wq  [b][e][c]
  short* Kb = p;   p += NX;       // K, V contiguous (stride NX)
  short* Vb = p;   p += NX;
  short* QMb = p;  p += NX;
  short* Vtb = p;  p += NX;
  int* flags = (int*)p;  p += 2048;  // 32x32 tile flags (4KB)
  short* AOb = Mtb;  // Mt+Gt region (8*NW == NX shorts) dead after QM -> reuse for AO

  cvt_f32_bf16<<<NX / 2048, 256, 0, stream>>>(x, xb, NX);
  cvt_f32_bf16<<<NW / 2048, 256, 0, stream>>>(Wk, wkb, NW);
  cvt_f32_bf16<<<NW / 2048, 256, 0, stream>>>(Wv, wvb, NW);
  cvt_f32_bf16<<<NW / 2048, 256, 0, stream>>>(Wo, wob, NW);
  cvtT_M<<<dim3(16, 16, 1), 256, 0, stream>>>(Wq, wqt);   // Wq^T
  cvtT_M<<<dim3(16, 16, 4), 256, 0, stream>>>(M, Mtb);    // M^T per batch
  mask_flags<<<dim3(32, 32), 256, 0, stream>>>(mask, flags);

  // K,V = x W{k,v}^T in one batched launch (A shared via sA=0)
  gemm_bt<short><<<dim3(64, 8, 2), 256, 0, stream>>>(xb, wkb, Kb, 8192, 1024, 1024,
                                                     0, NW, NX, 1.0f);
  // G^T[b][e][c] = sum_d Mt[b][e][d] * Wqt[c][d]  (= (Wq^T M)^T, 8.6 GF)
  gemm_bt<short><<<dim3(8, 8, 4), 256, 0, stream>>>(Mtb, wqt, Gtb, 1024, 1024, 1024,
                                                    NW, 0, NW, 1.0f);
  // QM[b][s][e] = C1 * sum_c x[b][s][c] * Gt[b][e][c]  (fused Q-proj + bilinear,
  // pre-scaled into the log2-softmax domain for flash)
  gemm_bt<short><<<dim3(16, 8, 4), 256, 0, stream>>>(xb, Gtb, QMb, 2048, 1024, 1024,
                                                     S * D, NW, S * D, C1);
  transposeV<<<dim3(32, 16, 4), 256, 0, stream>>>(Vb, Vtb);
  flash_attn<<<dim3(16, 16, 4), 512, 0, stream>>>(QMb, Kb, Vtb, mask, flags, AOb);
  // out = AO @ Wo^T (f32 store)
  gemm_bt<float><<<dim3(64, 8, 1), 256, 0, stream>>>(AOb, wob, out, 8192, 1024, 1024,
                                                     0, 0, 0, 1.0f);
}